// Round 14
// baseline (1196.053 us; speedup 1.0000x reference)
//
#include <hip/hip_runtime.h>
#include <hip/hip_bf16.h>

#define D_MODEL 1024
#define NHEAD   16
#define HDIM    64
#define DFF_    4096
#define TM_     512
#define TA_     512
#define BATCH   32
#define NTOK    (TM_ * BATCH)   // 16384 tokens
#define NBEATS_ 64

typedef __bf16 bfv8 __attribute__((ext_vector_type(8)));
typedef float  f32x4 __attribute__((ext_vector_type(4)));
typedef unsigned short u16x8 __attribute__((ext_vector_type(8)));
typedef unsigned short u16x4 __attribute__((ext_vector_type(4)));

__device__ __forceinline__ unsigned short f2bf(float f) {
  union { float f; unsigned u; } v; v.f = f;
  unsigned r = v.u + 0x7fffu + ((v.u >> 16) & 1u);   // RNE
  return (unsigned short)(r >> 16);
}
__device__ __forceinline__ float bf2f(unsigned short h) {
  union { unsigned u; float f; } v; v.u = ((unsigned)h) << 16;
  return v.f;
}
// packed bf16 pair (compiler emits v_cvt_pk_bf16_f32)
__device__ __forceinline__ unsigned pk2bf(float a, float b) {
  __hip_bfloat162 t = __float22bfloat162_rn(make_float2(a, b));
  union { __hip_bfloat162 h; unsigned u; } v; v.h = t;
  return v.u;
}
// fast GELU (tanh form): th = 1 - 2/(e^{2u}+1); limits correct at +-inf.
__device__ __forceinline__ float gelu_fast(float v) {
  float t = v * v;
  float e = __expf(v * fmaf(0.0713554f, t, 1.5957691f));   // e^{2u}
  float r = __builtin_amdgcn_rcpf(e + 1.0f);
  return v - v * r;                                        // v*(1-r) = 0.5v(1+th)
}

// direct-to-LDS 16B async copy (per-lane global addr, wave-uniform LDS base + lane*16)
#define GLOAD_LDS16(g, l) __builtin_amdgcn_global_load_lds( \
    (const __attribute__((address_space(1))) unsigned int*)(g), \
    (__attribute__((address_space(3))) unsigned int*)(l), 16, 0, 0)

#define MEMFENCE asm volatile("" ::: "memory")
#define BARRIER  do { MEMFENCE; __builtin_amdgcn_s_barrier(); MEMFENCE; } while (0)

// ---------------------------------------------------------------- fallback (ws too small diagnostic)
__global__ __launch_bounds__(256) void copy_f32(const float* __restrict__ in, float* __restrict__ out) {
  long i = ((long)blockIdx.x * 256 + threadIdx.x) * 4;
  *(float4*)(out + i) = *(const float4*)(in + i);
}

// ---------------------------------------------------------------- converts
__global__ __launch_bounds__(256) void cvt_f32_bf16(
    const float* __restrict__ in, unsigned short* __restrict__ out) {
  long i = ((long)blockIdx.x * 256 + threadIdx.x) * 4;
  float4 v = *(const float4*)(in + i);
  u16x4 o = { f2bf(v.x), f2bf(v.y), f2bf(v.z), f2bf(v.w) };
  *(u16x4*)(out + i) = o;
}

// (t,b,d) f32 -> rows (b*512+t) bf16. blockIdx.x = input row (t*32+b).
__global__ __launch_bounds__(256) void cvt_remap_bt(
    const float* __restrict__ in, unsigned short* __restrict__ out) {
  long rin = blockIdx.x;
  int b = (int)(rin & 31), t = (int)(rin >> 5);
  long rout = (long)b * 512 + t;
  int c = threadIdx.x * 4;
  float4 v = *(const float4*)(in + rin * 1024 + c);
  u16x4 o = { f2bf(v.x), f2bf(v.y), f2bf(v.z), f2bf(v.w) };
  *(u16x4*)(out + rout * 1024 + c) = o;
}

// ---------------------------------------------------------------- bias precompute (TRANSPOSED: biasT[ta][tm])
__global__ __launch_bounds__(512) void build_biasT(
    const int* __restrict__ beats, float* __restrict__ biasT) {
  int ta = blockIdx.x;        // 512
  int tm = threadIdx.x;       // 512
  float m = 0.f;
  for (int i = 0; i < NBEATS_; ++i) {
    int bf = beats[i];
    if (bf == ta) m = fmaxf(m, 2.0f);
    if (bf > 0 && bf - 1 == ta) m = fmaxf(m, 1.0f);
    if (bf < TA_ - 1 && bf + 1 == ta) m = fmaxf(m, 1.0f);
  }
  float diff = (float)tm - (float)ta;   // scale = 1
  biasT[ta * TM_ + tm] = -(diff * diff) * (1.0f / 32.0f) + m;  // 2*sigma^2=32
}

// ---------------------------------------------------------------- GEMM 256x256 (round-12 verified, unchanged)
template<int EPI, int SWAP>
__global__ __launch_bounds__(512, 2) void gemm256p(
    const unsigned short* __restrict__ A, const unsigned short* __restrict__ Bw,
    const float* __restrict__ bias, int K,
    unsigned short* __restrict__ outP, int ldc,
    unsigned short* __restrict__ dq, unsigned short* __restrict__ dk,
    unsigned short* __restrict__ dv, int s1) {
  __shared__ __align__(16) unsigned short As[2][2][128 * 64];  // 64 KB
  __shared__ __align__(16) unsigned short Bs[2][2][128 * 64];  // 64 KB
  const int tid = threadIdx.x;
  const int w = tid >> 6, lane = tid & 63;
  const int l15 = lane & 15, l4 = lane >> 4;
  const int wm = w >> 2, wn = w & 3;            // 2 x 4 wave grid
  const long m0 = (long)blockIdx.x * 256;
  const long n0 = (long)blockIdx.y * 256;
  const int srow8 = lane >> 3;                  // dest row within 8-row slab
  const int scol = ((lane & 7) ^ srow8) * 8;    // pre-swizzled source col (elems)

  const unsigned short* bA00 = A  + (m0 +       (w * 2 + 0) * 8 + srow8) * (long)K + scol;
  const unsigned short* bA01 = A  + (m0 +       (w * 2 + 1) * 8 + srow8) * (long)K + scol;
  const unsigned short* bA10 = A  + (m0 + 128 + (w * 2 + 0) * 8 + srow8) * (long)K + scol;
  const unsigned short* bA11 = A  + (m0 + 128 + (w * 2 + 1) * 8 + srow8) * (long)K + scol;
  const unsigned short* bB00 = Bw + (n0 +       (w * 2 + 0) * 8 + srow8) * (long)K + scol;
  const unsigned short* bB01 = Bw + (n0 +       (w * 2 + 1) * 8 + srow8) * (long)K + scol;
  const unsigned short* bB10 = Bw + (n0 + 128 + (w * 2 + 0) * 8 + srow8) * (long)K + scol;
  const unsigned short* bB11 = Bw + (n0 + 128 + (w * 2 + 1) * 8 + srow8) * (long)K + scol;

  auto stA = [&](int kt, int h, const unsigned short* p0, const unsigned short* p1) {
    const int db = kt & 1;
    const long ko = (long)kt * 64;
    GLOAD_LDS16(p0 + ko, &As[db][h][(w * 2 + 0) * 512]);
    GLOAD_LDS16(p1 + ko, &As[db][h][(w * 2 + 1) * 512]);
  };
  auto stB = [&](int kt, int h, const unsigned short* p0, const unsigned short* p1) {
    const int db = kt & 1;
    const long ko = (long)kt * 64;
    GLOAD_LDS16(p0 + ko, &Bs[db][h][(w * 2 + 0) * 512]);
    GLOAD_LDS16(p1 + ko, &Bs[db][h][(w * 2 + 1) * 512]);
  };
  const int swzb0 = ((l4)     ^ (l15 & 7)) << 4;   // byte offset, kk=0
  const int swzb1 = ((l4 + 4) ^ (l15 & 7)) << 4;   // byte offset, kk=1
  auto rdfrag = [&](const unsigned short* buf, int r, int kk) -> bfv8 {
    return *(const bfv8*)((const char*)buf + r * 128 + (kk ? swzb1 : swzb0));
  };

  f32x4 acc[8][4] = {};
  bfv8 aF[4][2], bF[4][2];
  const int nt = K >> 6;
  const int hB = wn >> 1, rB0 = (wn & 1) * 64;

  stA(0, 0, bA00, bA01); stA(0, 1, bA10, bA11);
  stB(0, 0, bB00, bB01); stB(0, 1, bB10, bB11);
  stB(1, 0, bB00, bB01); stB(1, 1, bB10, bB11);
  stA(1, 0, bA00, bA01); stA(1, 1, bA10, bA11);
  asm volatile("s_waitcnt vmcnt(8)" ::: "memory");
  BARRIER;

  for (int t = 0; t < nt; ++t) {
    const int db = t & 1;
    const unsigned short* Ah = &As[db][wm][0];
    const unsigned short* Bh = &Bs[db][hB][0];
    const bool pf2 = (t + 2 < nt);

    // phase 0
#pragma unroll
    for (int mf = 0; mf < 4; ++mf) {
      aF[mf][0] = rdfrag(Ah, mf * 16 + l15, 0);
      aF[mf][1] = rdfrag(Ah, mf * 16 + l15, 1);
    }
#pragma unroll
    for (int nf = 0; nf < 2; ++nf) {
      bF[nf][0] = rdfrag(Bh, rB0 + nf * 16 + l15, 0);
      bF[nf][1] = rdfrag(Bh, rB0 + nf * 16 + l15, 1);
    }
    BARRIER;
    asm volatile("s_waitcnt lgkmcnt(0)" ::: "memory");
    __builtin_amdgcn_s_setprio(1);
#pragma unroll
    for (int mf = 0; mf < 4; ++mf)
#pragma unroll
      for (int nf = 0; nf < 2; ++nf)
#pragma unroll
        for (int kk = 0; kk < 2; ++kk)
          acc[mf][nf] = SWAP
            ? __builtin_amdgcn_mfma_f32_16x16x32_bf16(bF[nf][kk], aF[mf][kk], acc[mf][nf], 0, 0, 0)
            : __builtin_amdgcn_mfma_f32_16x16x32_bf16(aF[mf][kk], bF[nf][kk], acc[mf][nf], 0, 0, 0);
    __builtin_amdgcn_s_setprio(0);
    BARRIER;

    // phase 1
#pragma unroll
    for (int nf = 2; nf < 4; ++nf) {
      bF[nf][0] = rdfrag(Bh, rB0 + nf * 16 + l15, 0);
      bF[nf][1] = rdfrag(Bh, rB0 + nf * 16 + l15, 1);
    }
    BARRIER;
    asm volatile("s_waitcnt lgkmcnt(0)" ::: "memory");
    __builtin_amdgcn_s_setprio(1);
#pragma unroll
    for (int mf = 0; mf < 4; ++mf)
#pragma unroll
      for (int nf = 2; nf < 4; ++nf)
#pragma unroll
        for (int kk = 0; kk < 2; ++kk)
          acc[mf][nf] = SWAP
            ? __builtin_amdgcn_mfma_f32_16x16x32_bf16(bF[nf][kk], aF[mf][kk], acc[mf][nf], 0, 0, 0)
            : __builtin_amdgcn_mfma_f32_16x16x32_bf16(aF[mf][kk], bF[nf][kk], acc[mf][nf], 0, 0, 0);
    __builtin_amdgcn_s_setprio(0);
    BARRIER;

    // phase 2 (+ stage B(t+2))
#pragma unroll
    for (int mf = 0; mf < 4; ++mf) {
      aF[mf][0] = rdfrag(Ah, (mf + 4) * 16 + l15, 0);
      aF[mf][1] = rdfrag(Ah, (mf + 4) * 16 + l15, 1);
    }
    if (pf2) { stB(t + 2, 0, bB00, bB01); stB(t + 2, 1, bB10, bB11); }
    BARRIER;
    asm volatile("s_waitcnt lgkmcnt(0)" ::: "memory");
    __builtin_amdgcn_s_setprio(1);
#pragma unroll
    for (int mf = 0; mf < 4; ++mf)
#pragma unroll
      for (int nf = 0; nf < 2; ++nf)
#pragma unroll
        for (int kk = 0; kk < 2; ++kk)
          acc[mf + 4][nf] = SWAP
            ? __builtin_amdgcn_mfma_f32_16x16x32_bf16(bF[nf][kk], aF[mf][kk], acc[mf + 4][nf], 0, 0, 0)
            : __builtin_amdgcn_mfma_f32_16x16x32_bf16(aF[mf][kk], bF[nf][kk], acc[mf + 4][nf], 0, 0, 0);
    __builtin_amdgcn_s_setprio(0);
    BARRIER;

    // phase 3 (+ stage A(t+2), counted drain of t+1)
    if (pf2) { stA(t + 2, 0, bA00, bA01); stA(t + 2, 1, bA10, bA11); }
    __builtin_amdgcn_s_setprio(1);
#pragma unroll
    for (int mf = 0; mf < 4; ++mf)
#pragma unroll
      for (int nf = 2; nf < 4; ++nf)
#pragma unroll
        for (int kk = 0; kk < 2; ++kk)
          acc[mf + 4][nf] = SWAP
            ? __builtin_amdgcn_mfma_f32_16x16x32_bf16(bF[nf][kk], aF[mf][kk], acc[mf + 4][nf], 0, 0, 0)
            : __builtin_amdgcn_mfma_f32_16x16x32_bf16(aF[mf][kk], bF[nf][kk], acc[mf + 4][nf], 0, 0, 0);
    __builtin_amdgcn_s_setprio(0);
    if (pf2)                asm volatile("s_waitcnt vmcnt(8)" ::: "memory");
    else if (t + 1 < nt)    asm volatile("s_waitcnt vmcnt(0)" ::: "memory");
    BARRIER;
  }

  // epilogue (verified mappings)
#pragma unroll
  for (int mf = 0; mf < 8; ++mf)
#pragma unroll
    for (int nf = 0; nf < 4; ++nf) {
      if (SWAP) {
        const int mrow = (int)m0 + wm * 128 + mf * 16 + l15;
        const int col0 = (int)n0 + wn * 64 + nf * 16 + l4 * 4;
        float4 bv = bias ? *(const float4*)&bias[col0] : make_float4(0.f, 0.f, 0.f, 0.f);
        float v0 = acc[mf][nf][0] + bv.x, v1 = acc[mf][nf][1] + bv.y;
        float v2 = acc[mf][nf][2] + bv.z, v3 = acc[mf][nf][3] + bv.w;
        if (EPI == 1) { v0 = gelu_fast(v0); v1 = gelu_fast(v1); v2 = gelu_fast(v2); v3 = gelu_fast(v3); }
        if (EPI == 0 || EPI == 1) {
          uint2 ov; ov.x = pk2bf(v0, v1); ov.y = pk2bf(v2, v3);
          *(uint2*)&outP[(long)mrow * ldc + col0] = ov;
        } else {
          int b_ = mrow >> 9, t_ = mrow & 511;
          if (col0 < s1) {
            int h = col0 >> 6, d0 = col0 & 63;
            uint2 ov; ov.x = pk2bf(v0 * 0.125f, v1 * 0.125f); ov.y = pk2bf(v2 * 0.125f, v3 * 0.125f);
            *(uint2*)&dq[(((long)b_ * NHEAD + h) * TM_ + t_) * HDIM + d0] = ov;
          } else {
            int c0 = col0 - s1, h = c0 >> 6, d0 = c0 & 63;
            uint2 ov; ov.x = pk2bf(v0, v1); ov.y = pk2bf(v2, v3);
            *(uint2*)&dk[(((long)b_ * NHEAD + h) * TA_ + t_) * HDIM + d0] = ov;
          }
        }
      } else {
        const int col = (int)n0 + wn * 64 + nf * 16 + l15;
        const int row0 = (int)m0 + wm * 128 + mf * 16 + l4 * 4;
        float bv = bias ? bias[col] : 0.f;
        int b_ = row0 >> 9, t0 = row0 & 511;
        int h = col >> 6, d = col & 63;
        uint2 ov;
        ov.x = pk2bf(acc[mf][nf][0] + bv, acc[mf][nf][1] + bv);
        ov.y = pk2bf(acc[mf][nf][2] + bv, acc[mf][nf][3] + bv);
        *(uint2*)&dv[(((long)b_ * NHEAD + h) * HDIM + d) * TA_ + t0] = ov;
      }
    }
}

// ---------------------------------------------------------------- fused attention v7
// r12 skeleton (K staged dbuf via gload_lds, wave-private P_lds, swapped PV) +
// V PREFETCHED TO REGISTERS at iteration top (8x bfv8, ~1500cy of QK^T+softmax
// cover — fixes r13's serialized V-latency regression) + defer-max (T13, THR=8)
// + tree max/sum. LDS 24 KB.
template<int BIAS>
__global__ __launch_bounds__(256) void attn_fused7(
    const unsigned short* __restrict__ Qr, const unsigned short* __restrict__ Kr,
    const unsigned short* __restrict__ Vt, const float* __restrict__ biasT,
    unsigned short* __restrict__ Orow) {
  __shared__ __align__(16) unsigned short Kb[2][64 * 64];     // 16 KB
  __shared__ __align__(16) unsigned short P_lds[4][16][64];   // 8 KB
  const int flat = blockIdx.y * 8 + blockIdx.x;     // gridDim.x == 8
  const int W = (flat & 7) * 512 + (flat >> 3);     // XCD-chunked (bijective)
  const int bh = W >> 3;
  const int b = bh >> 4, h = bh & 15;
  const int tid = threadIdx.x, w = tid >> 6, lane = tid & 63;
  const int l15 = lane & 15, l4 = lane >> 4;
  const int q0 = (W & 7) * 64 + w * 16;

  const unsigned short* Kg = Kr + (long)bh * TA_ * HDIM;
  const unsigned short* Vg = Vt + (long)bh * HDIM * TA_;

  const int stg_row = w * 8 + (lane >> 3);
  const int stg_col = ((lane & 7) ^ (lane >> 3)) * 8;

  auto stage = [&](int t, int cb) {     // K only
    const int kv0 = t * 64;
#pragma unroll
    for (int i = 0; i < 2; ++i) {
      int row = i * 32 + stg_row;
      GLOAD_LDS16(Kg + (long)(kv0 + row) * HDIM + stg_col, &Kb[cb][(i * 32 + w * 8) * 64]);
    }
  };

  bfv8 qf[2];
#pragma unroll
  for (int kc = 0; kc < 2; ++kc)
    qf[kc] = *(const bfv8*)&Qr[((long)bh * TM_ + q0 + l15) * HDIM + kc * 32 + l4 * 8];

  float mrun = -1e30f, lrun = 0.f;
  f32x4 o[4] = {};   // o[fd] = O^T[d][q=l15]
  unsigned short* prow = &P_lds[w][l15][0];
  const int swz = (l15 & 7) * 8;

  stage(0, 0);
  __syncthreads();
  int cur = 0;

  for (int t = 0; t < 8; ++t) {
    if (t < 7) stage(t + 1, cur ^ 1);
    const int kv0 = t * 64;
    // ---- V prefetch to registers (issued BEFORE QK^T; consumed after softmax)
    bfv8 vr0[4], vr1[4];
#pragma unroll
    for (int fd = 0; fd < 4; ++fd) {
      vr0[fd] = *(const bfv8*)&Vg[(long)(fd * 16 + l15) * TA_ + kv0 + 0 * 32 + l4 * 8];
      vr1[fd] = *(const bfv8*)&Vg[(long)(fd * 16 + l15) * TA_ + kv0 + 1 * 32 + l4 * 8];
    }
    // ---- QK^T from staged K
    f32x4 s[4] = {};
#pragma unroll
    for (int f = 0; f < 4; ++f) {
#pragma unroll
      for (int kc = 0; kc < 2; ++kc) {
        bfv8 kf = *(const bfv8*)&Kb[cur][(f * 16 + l15) * 64 + (((kc * 4 + l4) * 8) ^ swz)];
        s[f] = __builtin_amdgcn_mfma_f32_16x16x32_bf16(kf, qf[kc], s[f], 0, 0, 0);
      }
    }
    if (BIAS) {
#pragma unroll
      for (int f = 0; f < 4; ++f)
#pragma unroll
        for (int r = 0; r < 4; ++r)
          s[f][r] += biasT[(long)(kv0 + f * 16 + l4 * 4 + r) * TM_ + q0 + l15];
    }
    // ---- tile max (tree; fuses to v_max3) + wave halves
    float t0 = fmaxf(fmaxf(s[0][0], s[0][1]), fmaxf(s[0][2], s[0][3]));
    float t1 = fmaxf(fmaxf(s[1][0], s[1][1]), fmaxf(s[1][2], s[1][3]));
    float t2 = fmaxf(fmaxf(s[2][0], s[2][1]), fmaxf(s[2][2], s[2][3]));
    float t3 = fmaxf(fmaxf(s[3][0], s[3][1]), fmaxf(s[3][2], s[3][3]));
    float pmax = fmaxf(fmaxf(t0, t1), fmaxf(t2, t3));
    pmax = fmaxf(pmax, __shfl_xor(pmax, 16));
    pmax = fmaxf(pmax, __shfl_xor(pmax, 32));
    // ---- defer-max (T13): only rescale when max grew past THR=8
    if (!__all(pmax - mrun <= 8.0f)) {
      float newm = fmaxf(mrun, pmax);
      float corr = __expf(mrun - newm);   // row q=l15 == O's lane row: direct rescale
      lrun *= corr;
#pragma unroll
      for (int fd = 0; fd < 4; ++fd)
#pragma unroll
        for (int r = 0; r < 4; ++r) o[fd][r] *= corr;
      mrun = newm;
    }
    // ---- exp (bounded by e^8) + pack/write P + psum tree
    float p0 = 0.f, p1 = 0.f, p2 = 0.f, p3 = 0.f;
#pragma unroll
    for (int f = 0; f < 4; ++f) {
      float e0 = __expf(s[f][0] - mrun), e1 = __expf(s[f][1] - mrun);
      float e2 = __expf(s[f][2] - mrun), e3 = __expf(s[f][3] - mrun);
      p0 += e0; p1 += e1; p2 += e2; p3 += e3;
      unsigned w0 = pk2bf(e0, e1);
      unsigned w1 = pk2bf(e2, e3);
      int blkW = ((f << 1) | (l4 >> 1)) ^ (l15 & 7);
      uint2 pw; pw.x = w0; pw.y = w1;
      *(uint2*)((char*)prow + blkW * 16 + (l4 & 1) * 8) = pw;
    }
    float psum = (p0 + p1) + (p2 + p3);
    psum += __shfl_xor(psum, 16);
    psum += __shfl_xor(psum, 32);
    lrun += psum;
    asm volatile("s_waitcnt lgkmcnt(0)" ::: "memory");
    __builtin_amdgcn_sched_barrier(0);   // rule #18
    // ---- PV from register V (already resident)
#pragma unroll
    for (int c = 0; c < 2; ++c) {
      int blkR = ((c << 2) | l4) ^ (l15 & 7);
      bfv8 pa = *(const bfv8*)((const char*)prow + blkR * 16);
#pragma unroll
      for (int fd = 0; fd < 4; ++fd) {
        bfv8 vb = c ? vr1[fd] : vr0[fd];
        o[fd] = __builtin_amdgcn_mfma_f32_16x16x32_bf16(vb, pa, o[fd], 0, 0, 0);  // swapped
      }
    }
    __syncthreads();   // Kb[cur^1] staged + all waves done reading Kb[cur]
    cur ^= 1;
  }

  float invl = 1.f / lrun;
  const long obase = ((long)b * 512 + q0 + l15) * D_MODEL + h * HDIM;
#pragma unroll
  for (int fd = 0; fd < 4; ++fd) {
    uint2 ov;
    ov.x = pk2bf(o[fd][0] * invl, o[fd][1] * invl);
    ov.y = pk2bf(o[fd][2] * invl, o[fd][3] * invl);
    *(uint2*)&Orow[obase + fd * 16 + l4 * 4] = ov;
  }
}

// ---------------------------------------------------------------- fused residual + LayerNorm
__global__ __launch_bounds__(256) void ln_fused(
    const unsigned short* __restrict__ cin,
    const float* __restrict__ residf, const unsigned short* __restrict__ residb,
    const float* __restrict__ gamma, const float* __restrict__ beta,
    const float* __restrict__ gate,
    float* __restrict__ out_f32, unsigned short* __restrict__ out_bf16,
    int remap_resid, int remap_out) {
  long row = blockIdx.x;
  int t = threadIdx.x;
  int tt = (int)(row & 511), bb = (int)(row >> 9);
  long row_tb = (long)tt * 32 + bb;
  float gf = gate ? tanhf(gate[0]) : 1.0f;
  u16x4 cvb = *(const u16x4*)(cin + row * 1024 + t * 4);
  float c0 = bf2f(cvb[0]), c1 = bf2f(cvb[1]), c2 = bf2f(cvb[2]), c3 = bf2f(cvb[3]);
  float r0, r1, r2, r3;
  if (residf) {
    long rr = remap_resid ? row_tb : row;
    float4 rv = *(const float4*)(residf + rr * 1024 + t * 4);
    r0 = rv.x; r1 = rv.y; r2 = rv.z; r3 = rv.w;
  } else {
    u16x4 rv = *(const u16x4*)(residb + row * 1024 + t * 4);
    r0 = bf2f(rv[0]); r1 = bf2f(rv[1]); r2 = bf2f(rv[2]); r3 = bf2f(rv[3]);
  }
  float y0 = r0 + gf * c0, y1 = r1 + gf * c1, y2 = r2 + gf * c2, y3 = r3 + gf * c3;
  float s = y0 + y1 + y2 + y3;
  float q = y0 * y0 + y1 * y1 + y2 * y2 + y3 * y3;
#pragma unroll
  for (int off = 32; off; off >>= 1) { s += __shfl_xor(s, off); q += __shfl_xor(q, off); }
  __shared__ float sw[4], qw[4];
  int wave = t >> 6;
  if ((t & 63) == 0) { sw[wave] = s; qw[wave] = q; }
  __syncthreads();
  s = sw[0] + sw[1] + sw[2] + sw[3];
  q = qw[0] + qw[1] + qw[2] + qw[3];
  float mean = s * (1.0f / 1024.0f);
  float var = q * (1.0f / 1024.0f) - mean * mean;
  float rstd = rsqrtf(var + 1e-5f);
  float4 g4 = *(const float4*)(gamma + t * 4);
  float4 b4 = *(const float4*)(beta + t * 4);
  float o0 = (y0 - mean) * rstd * g4.x + b4.x;
  float o1 = (y1 - mean) * rstd * g4.y + b4.y;
  float o2 = (y2 - mean) * rstd * g4.z + b4.z;
  float o3 = (y3 - mean) * rstd * g4.w + b4.w;
  if (out_f32) {
    long ro = remap_out ? row_tb : row;
    float4 o = { o0, o1, o2, o3 };
    *(float4*)(out_f32 + ro * 1024 + t * 4) = o;
  }
  if (out_bf16) {
    u16x4 ob = { f2bf(o0), f2bf(o1), f2bf(o2), f2bf(o3) };
    *(u16x4*)(out_bf16 + row * 1024 + t * 4) = ob;
  }
}

// ---------------------------------------------------------------- host
static inline char* wsa(char*& p, size_t bytes) {
  char* r = p;
  p += (bytes + 255) & ~(size_t)255;
  return r;
}

extern "C" void kernel_launch(void* const* d_in, const int* in_sizes, int n_in,
                              void* d_out, int out_size, void* d_ws, size_t ws_size,
                              hipStream_t stream) {
  const float* src      = (const float*)d_in[0];
  const float* audio    = (const float*)d_in[1];
  const int*   beats    = (const int*)d_in[2];
  const float* sa_in_w  = (const float*)d_in[3];
  const float* sa_in_b  = (const float*)d_in[4];
  const float* sa_out_w = (const float*)d_in[5];
  const float* sa_out_b = (const float*)d_in[6];
  const float* ca_in_w  = (const float*)d_in[7];
  const float* ca_in_b  = (const float*)d_in[8];
  const float* ca_out_w = (const float*)d_in[9];
  const float* ca_out_b = (const float*)d_in[10];
  const float* gate     = (const float*)d_in[11];
  const float* n1_g     = (const float*)d_in[12];
  const float* n1_b     = (const float*)d_in[13];
  const float* nc_g     = (const float*)d_in[14];
  const float* nc_b     = (const float*)d_in[15];
  const float* n2_g     = (const float*)d_in[16];
  const float* n2_b     = (const float*)d_in[17];
  const float* l1_w     = (const float*)d_in[18];
  const float* l1_b     = (const float*)d_in[19];
  const float* l2_w     = (const float*)d_in[20];
  const float* l2_b     = (const float*)d_in[21];
  float* out = (float*)d_out;
  (void)in_sizes; (void)n_in; (void)out_size;

  const size_t NEEDED = (size_t)236000000;
  if (ws_size < NEEDED) {
    copy_f32<<<dim3(NTOK), dim3(256), 0, stream>>>(src, out);
    return;
  }

  char* p = (char*)d_ws;
  float*          biasT  = (float*)         wsa(p, (size_t)TM_ * TA_ * 4);
  unsigned short* wsaiw  = (unsigned short*)wsa(p, (size_t)3 * D_MODEL * D_MODEL * 2);
  unsigned short* wsaow  = (unsigned short*)wsa(p, (size_t)D_MODEL * D_MODEL * 2);
  unsigned short* wcaiw  = (unsigned short*)wsa(p, (size_t)3 * D_MODEL * D_MODEL * 2);
  unsigned short* wcaow  = (unsigned short*)wsa(p, (size_t)D_MODEL * D_MODEL * 2);
  unsigned short* wl1    = (unsigned short*)wsa(p, (size_t)DFF_ * D_MODEL * 2);
  unsigned short* wl2    = (unsigned short*)wsa(p, (size_t)D_MODEL * DFF_ * 2);
  unsigned short* srcb   = (unsigned short*)wsa(p, (size_t)NTOK * D_MODEL * 2);
  unsigned short* audb   = (unsigned short*)wsa(p, (size_t)NTOK * D_MODEL * 2);
  // H1 (128 MiB) overlays [Qr | Kr | Vt | x1b]:
  unsigned short* Qr     = (unsigned short*)wsa(p, (size_t)NTOK * D_MODEL * 2);
  unsigned short* Kr     = (unsigned short*)wsa(p, (size_t)NTOK * D_MODEL * 2);
  unsigned short* Vt     = (unsigned short*)wsa(p, (size_t)NTOK * D_MODEL * 2);
  unsigned short* x1b    = (unsigned short*)wsa(p, (size_t)NTOK * D_MODEL * 2);
  unsigned short* Orow   = srcb;
  unsigned short* C1     = Vt;
  unsigned short* x2b    = audb;
  unsigned short* H1     = Qr;
  unsigned short* C2     = srcb;

  // ---- bias + converts
  build_biasT<<<dim3(TA_), dim3(TM_), 0, stream>>>(beats, biasT);
  cvt_remap_bt<<<dim3(NTOK), dim3(256), 0, stream>>>(src, srcb);
  cvt_remap_bt<<<dim3(NTOK), dim3(256), 0, stream>>>(audio, audb);
  cvt_f32_bf16<<<dim3((3 * D_MODEL * D_MODEL) / 1024), dim3(256), 0, stream>>>(sa_in_w, wsaiw);
  cvt_f32_bf16<<<dim3((D_MODEL * D_MODEL) / 1024), dim3(256), 0, stream>>>(sa_out_w, wsaow);
  cvt_f32_bf16<<<dim3((3 * D_MODEL * D_MODEL) / 1024), dim3(256), 0, stream>>>(ca_in_w, wcaiw);
  cvt_f32_bf16<<<dim3((D_MODEL * D_MODEL) / 1024), dim3(256), 0, stream>>>(ca_out_w, wcaow);
  cvt_f32_bf16<<<dim3((DFF_ * D_MODEL) / 1024), dim3(256), 0, stream>>>(l1_w, wl1);
  cvt_f32_bf16<<<dim3((D_MODEL * DFF_) / 1024), dim3(256), 0, stream>>>(l2_w, wl2);

  // ---- self-attention
  gemm256p<3, 1><<<dim3(64, 8), dim3(512), 0, stream>>>(
      srcb, wsaiw, sa_in_b, 1024, nullptr, 0, Qr, Kr, nullptr, 1024);
  gemm256p<2, 0><<<dim3(64, 4), dim3(512), 0, stream>>>(
      srcb, wsaiw + (size_t)2048 * D_MODEL, sa_in_b + 2048, 1024,
      nullptr, 0, nullptr, nullptr, Vt, 0);
  attn_fused7<0><<<dim3(TM_ / 64, BATCH * NHEAD), dim3(256), 0, stream>>>(Qr, Kr, Vt, nullptr, Orow);
  gemm256p<0, 1><<<dim3(64, 4), dim3(512), 0, stream>>>(
      Orow, wsaow, sa_out_b, 1024, C1, 1024, nullptr, nullptr, nullptr, 0);
  ln_fused<<<dim3(NTOK), dim3(256), 0, stream>>>(
      C1, src, nullptr, n1_g, n1_b, nullptr, nullptr, x1b, 1, 0);

  // ---- cross-attention
  gemm256p<3, 1><<<dim3(64, 4), dim3(512), 0, stream>>>(
      x1b, wcaiw, ca_in_b, 1024, nullptr, 0, Qr, nullptr, nullptr, 1024);      // all -> Q
  gemm256p<3, 1><<<dim3(64, 4), dim3(512), 0, stream>>>(
      audb, wcaiw + (size_t)1024 * D_MODEL, ca_in_b + 1024, 1024,
      nullptr, 0, nullptr, Kr, nullptr, 0);                                    // all -> K
  gemm256p<2, 0><<<dim3(64, 4), dim3(512), 0, stream>>>(
      audb, wcaiw + (size_t)2048 * D_MODEL, ca_in_b + 2048, 1024,
      nullptr, 0, nullptr, nullptr, Vt, 0);
  attn_fused7<1><<<dim3(TM_ / 64, BATCH * NHEAD), dim3(256), 0, stream>>>(Qr, Kr, Vt, biasT, Orow);
  gemm256p<0, 1><<<dim3(64, 4), dim3(512), 0, stream>>>(
      Orow, wcaow, ca_out_b, 1024, C1, 1024, nullptr, nullptr, nullptr, 0);
  ln_fused<<<dim3(NTOK), dim3(256), 0, stream>>>(
      C1, nullptr, x1b, nc_g, nc_b, gate, nullptr, x2b, 0, 0);

  // ---- FFN
  gemm256p<1, 1><<<dim3(64, 16), dim3(512), 0, stream>>>(
      x2b, wl1, l1_b, 1024, H1, DFF_, nullptr, nullptr, nullptr, 0);
  gemm256p<0, 1><<<dim3(64, 4), dim3(512), 0, stream>>>(
      H1, wl2, l2_b, DFF_, C2, 1024, nullptr, nullptr, nullptr, 0);
  ln_fused<<<dim3(NTOK), dim3(256), 0, stream>>>(
      C2, nullptr, x2b, n2_g, n2_b, nullptr, out, nullptr, 0, 1);
}

// Round 15
// 1008.324 us; speedup vs baseline: 1.1862x; 1.1862x over previous
//
#include <hip/hip_runtime.h>
#include <hip/hip_bf16.h>

#define D_MODEL 1024
#define NHEAD   16
#define HDIM    64
#define DFF_    4096
#define TM_     512
#define TA_     512
#define BATCH   32
#define NTOK    (TM_ * BATCH)   // 16384 tokens
#define NBEATS_ 64

typedef __bf16 bfv8 __attribute__((ext_vector_type(8)));
typedef float  f32x4 __attribute__((ext_vector_type(4)));
typedef unsigned short u16x8 __attribute__((ext_vector_type(8)));
typedef unsigned short u16x4 __attribute__((ext_vector_type(4)));

__device__ __forceinline__ unsigned short f2bf(float f) {
  union { float f; unsigned u; } v; v.f = f;
  unsigned r = v.u + 0x7fffu + ((v.u >> 16) & 1u);   // RNE
  return (unsigned short)(r >> 16);
}
__device__ __forceinline__ float bf2f(unsigned short h) {
  union { unsigned u; float f; } v; v.u = ((unsigned)h) << 16;
  return v.f;
}
// packed bf16 pair (compiler emits v_cvt_pk_bf16_f32)
__device__ __forceinline__ unsigned pk2bf(float a, float b) {
  __hip_bfloat162 t = __float22bfloat162_rn(make_float2(a, b));
  union { __hip_bfloat162 h; unsigned u; } v; v.h = t;
  return v.u;
}
// fast GELU (tanh form): th = 1 - 2/(e^{2u}+1); limits correct at +-inf.
__device__ __forceinline__ float gelu_fast(float v) {
  float t = v * v;
  float e = __expf(v * fmaf(0.0713554f, t, 1.5957691f));   // e^{2u}
  float r = __builtin_amdgcn_rcpf(e + 1.0f);
  return v - v * r;                                        // v*(1-r) = 0.5v(1+th)
}

// direct-to-LDS 16B async copy (per-lane global addr, wave-uniform LDS base + lane*16)
#define GLOAD_LDS16(g, l) __builtin_amdgcn_global_load_lds( \
    (const __attribute__((address_space(1))) unsigned int*)(g), \
    (__attribute__((address_space(3))) unsigned int*)(l), 16, 0, 0)

#define MEMFENCE asm volatile("" ::: "memory")
#define BARRIER  do { MEMFENCE; __builtin_amdgcn_s_barrier(); MEMFENCE; } while (0)

// ---------------------------------------------------------------- fallback (ws too small diagnostic)
__global__ __launch_bounds__(256) void copy_f32(const float* __restrict__ in, float* __restrict__ out) {
  long i = ((long)blockIdx.x * 256 + threadIdx.x) * 4;
  *(float4*)(out + i) = *(const float4*)(in + i);
}

// ---------------------------------------------------------------- converts
__global__ __launch_bounds__(256) void cvt_f32_bf16(
    const float* __restrict__ in, unsigned short* __restrict__ out) {
  long i = ((long)blockIdx.x * 256 + threadIdx.x) * 4;
  float4 v = *(const float4*)(in + i);
  u16x4 o = { f2bf(v.x), f2bf(v.y), f2bf(v.z), f2bf(v.w) };
  *(u16x4*)(out + i) = o;
}

// (t,b,d) f32 -> rows (b*512+t) bf16. blockIdx.x = input row (t*32+b).
__global__ __launch_bounds__(256) void cvt_remap_bt(
    const float* __restrict__ in, unsigned short* __restrict__ out) {
  long rin = blockIdx.x;
  int b = (int)(rin & 31), t = (int)(rin >> 5);
  long rout = (long)b * 512 + t;
  int c = threadIdx.x * 4;
  float4 v = *(const float4*)(in + rin * 1024 + c);
  u16x4 o = { f2bf(v.x), f2bf(v.y), f2bf(v.z), f2bf(v.w) };
  *(u16x4*)(out + rout * 1024 + c) = o;
}

// ---------------------------------------------------------------- bias precompute (TRANSPOSED: biasT[ta][tm])
__global__ __launch_bounds__(512) void build_biasT(
    const int* __restrict__ beats, float* __restrict__ biasT) {
  int ta = blockIdx.x;        // 512
  int tm = threadIdx.x;       // 512
  float m = 0.f;
  for (int i = 0; i < NBEATS_; ++i) {
    int bf = beats[i];
    if (bf == ta) m = fmaxf(m, 2.0f);
    if (bf > 0 && bf - 1 == ta) m = fmaxf(m, 1.0f);
    if (bf < TA_ - 1 && bf + 1 == ta) m = fmaxf(m, 1.0f);
  }
  float diff = (float)tm - (float)ta;   // scale = 1
  biasT[ta * TM_ + tm] = -(diff * diff) * (1.0f / 32.0f) + m;  // 2*sigma^2=32
}

// ---------------------------------------------------------------- GEMM 256x256 (round-12 verified, unchanged)
template<int EPI, int SWAP>
__global__ __launch_bounds__(512, 2) void gemm256p(
    const unsigned short* __restrict__ A, const unsigned short* __restrict__ Bw,
    const float* __restrict__ bias, int K,
    unsigned short* __restrict__ outP, int ldc,
    unsigned short* __restrict__ dq, unsigned short* __restrict__ dk,
    unsigned short* __restrict__ dv, int s1) {
  __shared__ __align__(16) unsigned short As[2][2][128 * 64];  // 64 KB
  __shared__ __align__(16) unsigned short Bs[2][2][128 * 64];  // 64 KB
  const int tid = threadIdx.x;
  const int w = tid >> 6, lane = tid & 63;
  const int l15 = lane & 15, l4 = lane >> 4;
  const int wm = w >> 2, wn = w & 3;            // 2 x 4 wave grid
  const long m0 = (long)blockIdx.x * 256;
  const long n0 = (long)blockIdx.y * 256;
  const int srow8 = lane >> 3;                  // dest row within 8-row slab
  const int scol = ((lane & 7) ^ srow8) * 8;    // pre-swizzled source col (elems)

  const unsigned short* bA00 = A  + (m0 +       (w * 2 + 0) * 8 + srow8) * (long)K + scol;
  const unsigned short* bA01 = A  + (m0 +       (w * 2 + 1) * 8 + srow8) * (long)K + scol;
  const unsigned short* bA10 = A  + (m0 + 128 + (w * 2 + 0) * 8 + srow8) * (long)K + scol;
  const unsigned short* bA11 = A  + (m0 + 128 + (w * 2 + 1) * 8 + srow8) * (long)K + scol;
  const unsigned short* bB00 = Bw + (n0 +       (w * 2 + 0) * 8 + srow8) * (long)K + scol;
  const unsigned short* bB01 = Bw + (n0 +       (w * 2 + 1) * 8 + srow8) * (long)K + scol;
  const unsigned short* bB10 = Bw + (n0 + 128 + (w * 2 + 0) * 8 + srow8) * (long)K + scol;
  const unsigned short* bB11 = Bw + (n0 + 128 + (w * 2 + 1) * 8 + srow8) * (long)K + scol;

  auto stA = [&](int kt, int h, const unsigned short* p0, const unsigned short* p1) {
    const int db = kt & 1;
    const long ko = (long)kt * 64;
    GLOAD_LDS16(p0 + ko, &As[db][h][(w * 2 + 0) * 512]);
    GLOAD_LDS16(p1 + ko, &As[db][h][(w * 2 + 1) * 512]);
  };
  auto stB = [&](int kt, int h, const unsigned short* p0, const unsigned short* p1) {
    const int db = kt & 1;
    const long ko = (long)kt * 64;
    GLOAD_LDS16(p0 + ko, &Bs[db][h][(w * 2 + 0) * 512]);
    GLOAD_LDS16(p1 + ko, &Bs[db][h][(w * 2 + 1) * 512]);
  };
  const int swzb0 = ((l4)     ^ (l15 & 7)) << 4;   // byte offset, kk=0
  const int swzb1 = ((l4 + 4) ^ (l15 & 7)) << 4;   // byte offset, kk=1
  auto rdfrag = [&](const unsigned short* buf, int r, int kk) -> bfv8 {
    return *(const bfv8*)((const char*)buf + r * 128 + (kk ? swzb1 : swzb0));
  };

  f32x4 acc[8][4] = {};
  bfv8 aF[4][2], bF[4][2];
  const int nt = K >> 6;
  const int hB = wn >> 1, rB0 = (wn & 1) * 64;

  stA(0, 0, bA00, bA01); stA(0, 1, bA10, bA11);
  stB(0, 0, bB00, bB01); stB(0, 1, bB10, bB11);
  stB(1, 0, bB00, bB01); stB(1, 1, bB10, bB11);
  stA(1, 0, bA00, bA01); stA(1, 1, bA10, bA11);
  asm volatile("s_waitcnt vmcnt(8)" ::: "memory");
  BARRIER;

  for (int t = 0; t < nt; ++t) {
    const int db = t & 1;
    const unsigned short* Ah = &As[db][wm][0];
    const unsigned short* Bh = &Bs[db][hB][0];
    const bool pf2 = (t + 2 < nt);

    // phase 0
#pragma unroll
    for (int mf = 0; mf < 4; ++mf) {
      aF[mf][0] = rdfrag(Ah, mf * 16 + l15, 0);
      aF[mf][1] = rdfrag(Ah, mf * 16 + l15, 1);
    }
#pragma unroll
    for (int nf = 0; nf < 2; ++nf) {
      bF[nf][0] = rdfrag(Bh, rB0 + nf * 16 + l15, 0);
      bF[nf][1] = rdfrag(Bh, rB0 + nf * 16 + l15, 1);
    }
    BARRIER;
    asm volatile("s_waitcnt lgkmcnt(0)" ::: "memory");
    __builtin_amdgcn_s_setprio(1);
#pragma unroll
    for (int mf = 0; mf < 4; ++mf)
#pragma unroll
      for (int nf = 0; nf < 2; ++nf)
#pragma unroll
        for (int kk = 0; kk < 2; ++kk)
          acc[mf][nf] = SWAP
            ? __builtin_amdgcn_mfma_f32_16x16x32_bf16(bF[nf][kk], aF[mf][kk], acc[mf][nf], 0, 0, 0)
            : __builtin_amdgcn_mfma_f32_16x16x32_bf16(aF[mf][kk], bF[nf][kk], acc[mf][nf], 0, 0, 0);
    __builtin_amdgcn_s_setprio(0);
    BARRIER;

    // phase 1
#pragma unroll
    for (int nf = 2; nf < 4; ++nf) {
      bF[nf][0] = rdfrag(Bh, rB0 + nf * 16 + l15, 0);
      bF[nf][1] = rdfrag(Bh, rB0 + nf * 16 + l15, 1);
    }
    BARRIER;
    asm volatile("s_waitcnt lgkmcnt(0)" ::: "memory");
    __builtin_amdgcn_s_setprio(1);
#pragma unroll
    for (int mf = 0; mf < 4; ++mf)
#pragma unroll
      for (int nf = 2; nf < 4; ++nf)
#pragma unroll
        for (int kk = 0; kk < 2; ++kk)
          acc[mf][nf] = SWAP
            ? __builtin_amdgcn_mfma_f32_16x16x32_bf16(bF[nf][kk], aF[mf][kk], acc[mf][nf], 0, 0, 0)
            : __builtin_amdgcn_mfma_f32_16x16x32_bf16(aF[mf][kk], bF[nf][kk], acc[mf][nf], 0, 0, 0);
    __builtin_amdgcn_s_setprio(0);
    BARRIER;

    // phase 2 (+ stage B(t+2))
#pragma unroll
    for (int mf = 0; mf < 4; ++mf) {
      aF[mf][0] = rdfrag(Ah, (mf + 4) * 16 + l15, 0);
      aF[mf][1] = rdfrag(Ah, (mf + 4) * 16 + l15, 1);
    }
    if (pf2) { stB(t + 2, 0, bB00, bB01); stB(t + 2, 1, bB10, bB11); }
    BARRIER;
    asm volatile("s_waitcnt lgkmcnt(0)" ::: "memory");
    __builtin_amdgcn_s_setprio(1);
#pragma unroll
    for (int mf = 0; mf < 4; ++mf)
#pragma unroll
      for (int nf = 0; nf < 2; ++nf)
#pragma unroll
        for (int kk = 0; kk < 2; ++kk)
          acc[mf + 4][nf] = SWAP
            ? __builtin_amdgcn_mfma_f32_16x16x32_bf16(bF[nf][kk], aF[mf][kk], acc[mf + 4][nf], 0, 0, 0)
            : __builtin_amdgcn_mfma_f32_16x16x32_bf16(aF[mf][kk], bF[nf][kk], acc[mf + 4][nf], 0, 0, 0);
    __builtin_amdgcn_s_setprio(0);
    BARRIER;

    // phase 3 (+ stage A(t+2), counted drain of t+1)
    if (pf2) { stA(t + 2, 0, bA00, bA01); stA(t + 2, 1, bA10, bA11); }
    __builtin_amdgcn_s_setprio(1);
#pragma unroll
    for (int mf = 0; mf < 4; ++mf)
#pragma unroll
      for (int nf = 2; nf < 4; ++nf)
#pragma unroll
        for (int kk = 0; kk < 2; ++kk)
          acc[mf + 4][nf] = SWAP
            ? __builtin_amdgcn_mfma_f32_16x16x32_bf16(bF[nf][kk], aF[mf][kk], acc[mf + 4][nf], 0, 0, 0)
            : __builtin_amdgcn_mfma_f32_16x16x32_bf16(aF[mf][kk], bF[nf][kk], acc[mf + 4][nf], 0, 0, 0);
    __builtin_amdgcn_s_setprio(0);
    if (pf2)                asm volatile("s_waitcnt vmcnt(8)" ::: "memory");
    else if (t + 1 < nt)    asm volatile("s_waitcnt vmcnt(0)" ::: "memory");
    BARRIER;
  }

  // epilogue (verified mappings)
#pragma unroll
  for (int mf = 0; mf < 8; ++mf)
#pragma unroll
    for (int nf = 0; nf < 4; ++nf) {
      if (SWAP) {
        const int mrow = (int)m0 + wm * 128 + mf * 16 + l15;
        const int col0 = (int)n0 + wn * 64 + nf * 16 + l4 * 4;
        float4 bv = bias ? *(const float4*)&bias[col0] : make_float4(0.f, 0.f, 0.f, 0.f);
        float v0 = acc[mf][nf][0] + bv.x, v1 = acc[mf][nf][1] + bv.y;
        float v2 = acc[mf][nf][2] + bv.z, v3 = acc[mf][nf][3] + bv.w;
        if (EPI == 1) { v0 = gelu_fast(v0); v1 = gelu_fast(v1); v2 = gelu_fast(v2); v3 = gelu_fast(v3); }
        if (EPI == 0 || EPI == 1) {
          uint2 ov; ov.x = pk2bf(v0, v1); ov.y = pk2bf(v2, v3);
          *(uint2*)&outP[(long)mrow * ldc + col0] = ov;
        } else {
          int b_ = mrow >> 9, t_ = mrow & 511;
          if (col0 < s1) {
            int h = col0 >> 6, d0 = col0 & 63;
            uint2 ov; ov.x = pk2bf(v0 * 0.125f, v1 * 0.125f); ov.y = pk2bf(v2 * 0.125f, v3 * 0.125f);
            *(uint2*)&dq[(((long)b_ * NHEAD + h) * TM_ + t_) * HDIM + d0] = ov;
          } else {
            int c0 = col0 - s1, h = c0 >> 6, d0 = c0 & 63;
            uint2 ov; ov.x = pk2bf(v0, v1); ov.y = pk2bf(v2, v3);
            *(uint2*)&dk[(((long)b_ * NHEAD + h) * TA_ + t_) * HDIM + d0] = ov;
          }
        }
      } else {
        const int col = (int)n0 + wn * 64 + nf * 16 + l15;
        const int row0 = (int)m0 + wm * 128 + mf * 16 + l4 * 4;
        float bv = bias ? bias[col] : 0.f;
        int b_ = row0 >> 9, t0 = row0 & 511;
        int h = col >> 6, d = col & 63;
        uint2 ov;
        ov.x = pk2bf(acc[mf][nf][0] + bv, acc[mf][nf][1] + bv);
        ov.y = pk2bf(acc[mf][nf][2] + bv, acc[mf][nf][3] + bv);
        *(uint2*)&dv[(((long)b_ * NHEAD + h) * HDIM + d) * TA_ + t0] = ov;
      }
    }
}

// ---------------------------------------------------------------- fused attention v8
// r12's verified per-wave math (K+V staged dbuf via gload_lds, wave-private swizzled
// P_lds, swapped PV) with 8-WAVE BLOCKS (128 q-rows/block): staging per q halved,
// LDS 48 KB -> 3 blocks/CU x 8 waves = 24 waves (75% ceiling) vs r12's ~10.
// + defer-max (T13, THR=8) + tree max/psum (passed 0.03125 in r13/14).
template<int BIAS>
__global__ __launch_bounds__(512) void attn_fused8(
    const unsigned short* __restrict__ Qr, const unsigned short* __restrict__ Kr,
    const unsigned short* __restrict__ Vt, const float* __restrict__ biasT,
    unsigned short* __restrict__ Orow) {
  __shared__ __align__(16) unsigned short Kb[2][64 * 64];     // 16 KB
  __shared__ __align__(16) unsigned short Vb[2][64 * 64];     // 16 KB
  __shared__ __align__(16) unsigned short P_lds[8][16][64];   // 16 KB
  const int flat = blockIdx.y * 4 + blockIdx.x;     // gridDim.x == 4, 2048 blocks
  const int W = (flat & 7) * 256 + (flat >> 3);     // XCD-chunked (2048 % 8 == 0, bijective)
  const int bh = W >> 2;
  const int b = bh >> 4, h = bh & 15;
  const int tid = threadIdx.x, w = tid >> 6, lane = tid & 63;   // w in 0..7
  const int l15 = lane & 15, l4 = lane >> 4;
  const int q0 = (W & 3) * 128 + w * 16;            // this wave's 16 q rows

  const unsigned short* Kg = Kr + (long)bh * TA_ * HDIM;
  const unsigned short* Vg = Vt + (long)bh * HDIM * TA_;

  const int stg_row = lane >> 3;                    // row within wave's 8-row slab
  const int stg_col = ((lane & 7) ^ stg_row) * 8;   // pre-swizzled source col

  auto stage = [&](int t, int cb) {                 // wave w stages rows w*8..w*8+7 of K and V
    const int kv0 = t * 64;
    int row = w * 8 + stg_row;
    GLOAD_LDS16(Kg + (long)(kv0 + row) * HDIM + stg_col, &Kb[cb][(w * 8) * 64]);
    GLOAD_LDS16(Vg + (long)row * TA_ + kv0 + stg_col,    &Vb[cb][(w * 8) * 64]);
  };

  bfv8 qf[2];
#pragma unroll
  for (int kc = 0; kc < 2; ++kc)
    qf[kc] = *(const bfv8*)&Qr[((long)bh * TM_ + q0 + l15) * HDIM + kc * 32 + l4 * 8];

  float mrun = -1e30f, lrun = 0.f;
  f32x4 o[4] = {};   // o[fd] = O^T[d][q=l15]
  unsigned short* prow = &P_lds[w][l15][0];
  const int swz = (l15 & 7) * 8;

  stage(0, 0);
  __syncthreads();
  int cur = 0;

  for (int t = 0; t < 8; ++t) {
    if (t < 7) stage(t + 1, cur ^ 1);
    const int kv0 = t * 64;
    // ---- QK^T from staged K
    f32x4 s[4] = {};
#pragma unroll
    for (int f = 0; f < 4; ++f) {
#pragma unroll
      for (int kc = 0; kc < 2; ++kc) {
        bfv8 kf = *(const bfv8*)&Kb[cur][(f * 16 + l15) * 64 + (((kc * 4 + l4) * 8) ^ swz)];
        s[f] = __builtin_amdgcn_mfma_f32_16x16x32_bf16(kf, qf[kc], s[f], 0, 0, 0);
      }
    }
    if (BIAS) {
#pragma unroll
      for (int f = 0; f < 4; ++f)
#pragma unroll
        for (int r = 0; r < 4; ++r)
          s[f][r] += biasT[(long)(kv0 + f * 16 + l4 * 4 + r) * TM_ + q0 + l15];
    }
    // ---- tile max (tree; fuses to v_max3) + wave halves
    float t0 = fmaxf(fmaxf(s[0][0], s[0][1]), fmaxf(s[0][2], s[0][3]));
    float t1 = fmaxf(fmaxf(s[1][0], s[1][1]), fmaxf(s[1][2], s[1][3]));
    float t2 = fmaxf(fmaxf(s[2][0], s[2][1]), fmaxf(s[2][2], s[2][3]));
    float t3 = fmaxf(fmaxf(s[3][0], s[3][1]), fmaxf(s[3][2], s[3][3]));
    float pmax = fmaxf(fmaxf(t0, t1), fmaxf(t2, t3));
    pmax = fmaxf(pmax, __shfl_xor(pmax, 16));
    pmax = fmaxf(pmax, __shfl_xor(pmax, 32));
    // ---- defer-max (T13): only rescale when max grew past THR=8
    if (!__all(pmax - mrun <= 8.0f)) {
      float newm = fmaxf(mrun, pmax);
      float corr = __expf(mrun - newm);   // row q=l15 == O's lane row: direct rescale
      lrun *= corr;
#pragma unroll
      for (int fd = 0; fd < 4; ++fd)
#pragma unroll
        for (int r = 0; r < 4; ++r) o[fd][r] *= corr;
      mrun = newm;
    }
    // ---- exp (bounded by e^8) + pack/write P + psum tree
    float p0 = 0.f, p1 = 0.f, p2 = 0.f, p3 = 0.f;
#pragma unroll
    for (int f = 0; f < 4; ++f) {
      float e0 = __expf(s[f][0] - mrun), e1 = __expf(s[f][1] - mrun);
      float e2 = __expf(s[f][2] - mrun), e3 = __expf(s[f][3] - mrun);
      p0 += e0; p1 += e1; p2 += e2; p3 += e3;
      unsigned w0 = pk2bf(e0, e1);
      unsigned w1 = pk2bf(e2, e3);
      int blkW = ((f << 1) | (l4 >> 1)) ^ (l15 & 7);
      uint2 pw; pw.x = w0; pw.y = w1;
      *(uint2*)((char*)prow + blkW * 16 + (l4 & 1) * 8) = pw;
    }
    float psum = (p0 + p1) + (p2 + p3);
    psum += __shfl_xor(psum, 16);
    psum += __shfl_xor(psum, 32);
    lrun += psum;
    asm volatile("s_waitcnt lgkmcnt(0)" ::: "memory");
    __builtin_amdgcn_sched_barrier(0);   // rule #18
    // ---- PV from staged V (swapped -> O rows lane-local)
#pragma unroll
    for (int c = 0; c < 2; ++c) {
      int blkR = ((c << 2) | l4) ^ (l15 & 7);
      bfv8 pa = *(const bfv8*)((const char*)prow + blkR * 16);
#pragma unroll
      for (int fd = 0; fd < 4; ++fd) {
        bfv8 vb = *(const bfv8*)&Vb[cur][(fd * 16 + l15) * 64 + (((c * 4 + l4) * 8) ^ swz)];
        o[fd] = __builtin_amdgcn_mfma_f32_16x16x32_bf16(vb, pa, o[fd], 0, 0, 0);  // swapped
      }
    }
    __syncthreads();   // next tile staged + all waves done reading buf[cur]
    cur ^= 1;
  }

  float invl = 1.f / lrun;
  const long obase = ((long)b * 512 + q0 + l15) * D_MODEL + h * HDIM;
#pragma unroll
  for (int fd = 0; fd < 4; ++fd) {
    uint2 ov;
    ov.x = pk2bf(o[fd][0] * invl, o[fd][1] * invl);
    ov.y = pk2bf(o[fd][2] * invl, o[fd][3] * invl);
    *(uint2*)&Orow[obase + fd * 16 + l4 * 4] = ov;
  }
}

// ---------------------------------------------------------------- fused residual + LayerNorm
__global__ __launch_bounds__(256) void ln_fused(
    const unsigned short* __restrict__ cin,
    const float* __restrict__ residf, const unsigned short* __restrict__ residb,
    const float* __restrict__ gamma, const float* __restrict__ beta,
    const float* __restrict__ gate,
    float* __restrict__ out_f32, unsigned short* __restrict__ out_bf16,
    int remap_resid, int remap_out) {
  long row = blockIdx.x;
  int t = threadIdx.x;
  int tt = (int)(row & 511), bb = (int)(row >> 9);
  long row_tb = (long)tt * 32 + bb;
  float gf = gate ? tanhf(gate[0]) : 1.0f;
  u16x4 cvb = *(const u16x4*)(cin + row * 1024 + t * 4);
  float c0 = bf2f(cvb[0]), c1 = bf2f(cvb[1]), c2 = bf2f(cvb[2]), c3 = bf2f(cvb[3]);
  float r0, r1, r2, r3;
  if (residf) {
    long rr = remap_resid ? row_tb : row;
    float4 rv = *(const float4*)(residf + rr * 1024 + t * 4);
    r0 = rv.x; r1 = rv.y; r2 = rv.z; r3 = rv.w;
  } else {
    u16x4 rv = *(const u16x4*)(residb + row * 1024 + t * 4);
    r0 = bf2f(rv[0]); r1 = bf2f(rv[1]); r2 = bf2f(rv[2]); r3 = bf2f(rv[3]);
  }
  float y0 = r0 + gf * c0, y1 = r1 + gf * c1, y2 = r2 + gf * c2, y3 = r3 + gf * c3;
  float s = y0 + y1 + y2 + y3;
  float q = y0 * y0 + y1 * y1 + y2 * y2 + y3 * y3;
#pragma unroll
  for (int off = 32; off; off >>= 1) { s += __shfl_xor(s, off); q += __shfl_xor(q, off); }
  __shared__ float sw[4], qw[4];
  int wave = t >> 6;
  if ((t & 63) == 0) { sw[wave] = s; qw[wave] = q; }
  __syncthreads();
  s = sw[0] + sw[1] + sw[2] + sw[3];
  q = qw[0] + qw[1] + qw[2] + qw[3];
  float mean = s * (1.0f / 1024.0f);
  float var = q * (1.0f / 1024.0f) - mean * mean;
  float rstd = rsqrtf(var + 1e-5f);
  float4 g4 = *(const float4*)(gamma + t * 4);
  float4 b4 = *(const float4*)(beta + t * 4);
  float o0 = (y0 - mean) * rstd * g4.x + b4.x;
  float o1 = (y1 - mean) * rstd * g4.y + b4.y;
  float o2 = (y2 - mean) * rstd * g4.z + b4.z;
  float o3 = (y3 - mean) * rstd * g4.w + b4.w;
  if (out_f32) {
    long ro = remap_out ? row_tb : row;
    float4 o = { o0, o1, o2, o3 };
    *(float4*)(out_f32 + ro * 1024 + t * 4) = o;
  }
  if (out_bf16) {
    u16x4 ob = { f2bf(o0), f2bf(o1), f2bf(o2), f2bf(o3) };
    *(u16x4*)(out_bf16 + row * 1024 + t * 4) = ob;
  }
}

// ---------------------------------------------------------------- host
static inline char* wsa(char*& p, size_t bytes) {
  char* r = p;
  p += (bytes + 255) & ~(size_t)255;
  return r;
}

extern "C" void kernel_launch(void* const* d_in, const int* in_sizes, int n_in,
                              void* d_out, int out_size, void* d_ws, size_t ws_size,
                              hipStream_t stream) {
  const float* src      = (const float*)d_in[0];
  const float* audio    = (const float*)d_in[1];
  const int*   beats    = (const int*)d_in[2];
  const float* sa_in_w  = (const float*)d_in[3];
  const float* sa_in_b  = (const float*)d_in[4];
  const float* sa_out_w = (const float*)d_in[5];
  const float* sa_out_b = (const float*)d_in[6];
  const float* ca_in_w  = (const float*)d_in[7];
  const float* ca_in_b  = (const float*)d_in[8];
  const float* ca_out_w = (const float*)d_in[9];
  const float* ca_out_b = (const float*)d_in[10];
  const float* gate     = (const float*)d_in[11];
  const float* n1_g     = (const float*)d_in[12];
  const float* n1_b     = (const float*)d_in[13];
  const float* nc_g     = (const float*)d_in[14];
  const float* nc_b     = (const float*)d_in[15];
  const float* n2_g     = (const float*)d_in[16];
  const float* n2_b     = (const float*)d_in[17];
  const float* l1_w     = (const float*)d_in[18];
  const float* l1_b     = (const float*)d_in[19];
  const float* l2_w     = (const float*)d_in[20];
  const float* l2_b     = (const float*)d_in[21];
  float* out = (float*)d_out;
  (void)in_sizes; (void)n_in; (void)out_size;

  const size_t NEEDED = (size_t)236000000;
  if (ws_size < NEEDED) {
    copy_f32<<<dim3(NTOK), dim3(256), 0, stream>>>(src, out);
    return;
  }

  char* p = (char*)d_ws;
  float*          biasT  = (float*)         wsa(p, (size_t)TM_ * TA_ * 4);
  unsigned short* wsaiw  = (unsigned short*)wsa(p, (size_t)3 * D_MODEL * D_MODEL * 2);
  unsigned short* wsaow  = (unsigned short*)wsa(p, (size_t)D_MODEL * D_MODEL * 2);
  unsigned short* wcaiw  = (unsigned short*)wsa(p, (size_t)3 * D_MODEL * D_MODEL * 2);
  unsigned short* wcaow  = (unsigned short*)wsa(p, (size_t)D_MODEL * D_MODEL * 2);
  unsigned short* wl1    = (unsigned short*)wsa(p, (size_t)DFF_ * D_MODEL * 2);
  unsigned short* wl2    = (unsigned short*)wsa(p, (size_t)D_MODEL * DFF_ * 2);
  unsigned short* srcb   = (unsigned short*)wsa(p, (size_t)NTOK * D_MODEL * 2);
  unsigned short* audb   = (unsigned short*)wsa(p, (size_t)NTOK * D_MODEL * 2);
  // H1 (128 MiB) overlays [Qr | Kr | Vt | x1b]:
  unsigned short* Qr     = (unsigned short*)wsa(p, (size_t)NTOK * D_MODEL * 2);
  unsigned short* Kr     = (unsigned short*)wsa(p, (size_t)NTOK * D_MODEL * 2);
  unsigned short* Vt     = (unsigned short*)wsa(p, (size_t)NTOK * D_MODEL * 2);
  unsigned short* x1b    = (unsigned short*)wsa(p, (size_t)NTOK * D_MODEL * 2);
  unsigned short* Orow   = srcb;
  unsigned short* C1     = Vt;
  unsigned short* x2b    = audb;
  unsigned short* H1     = Qr;
  unsigned short* C2     = srcb;

  // ---- bias + converts
  build_biasT<<<dim3(TA_), dim3(TM_), 0, stream>>>(beats, biasT);
  cvt_remap_bt<<<dim3(NTOK), dim3(256), 0, stream>>>(src, srcb);
  cvt_remap_bt<<<dim3(NTOK), dim3(256), 0, stream>>>(audio, audb);
  cvt_f32_bf16<<<dim3((3 * D_MODEL * D_MODEL) / 1024), dim3(256), 0, stream>>>(sa_in_w, wsaiw);
  cvt_f32_bf16<<<dim3((D_MODEL * D_MODEL) / 1024), dim3(256), 0, stream>>>(sa_out_w, wsaow);
  cvt_f32_bf16<<<dim3((3 * D_MODEL * D_MODEL) / 1024), dim3(256), 0, stream>>>(ca_in_w, wcaiw);
  cvt_f32_bf16<<<dim3((D_MODEL * D_MODEL) / 1024), dim3(256), 0, stream>>>(ca_out_w, wcaow);
  cvt_f32_bf16<<<dim3((DFF_ * D_MODEL) / 1024), dim3(256), 0, stream>>>(l1_w, wl1);
  cvt_f32_bf16<<<dim3((D_MODEL * DFF_) / 1024), dim3(256), 0, stream>>>(l2_w, wl2);

  // ---- self-attention
  gemm256p<3, 1><<<dim3(64, 8), dim3(512), 0, stream>>>(
      srcb, wsaiw, sa_in_b, 1024, nullptr, 0, Qr, Kr, nullptr, 1024);
  gemm256p<2, 0><<<dim3(64, 4), dim3(512), 0, stream>>>(
      srcb, wsaiw + (size_t)2048 * D_MODEL, sa_in_b + 2048, 1024,
      nullptr, 0, nullptr, nullptr, Vt, 0);
  attn_fused8<0><<<dim3(TM_ / 128, BATCH * NHEAD), dim3(512), 0, stream>>>(Qr, Kr, Vt, nullptr, Orow);
  gemm256p<0, 1><<<dim3(64, 4), dim3(512), 0, stream>>>(
      Orow, wsaow, sa_out_b, 1024, C1, 1024, nullptr, nullptr, nullptr, 0);
  ln_fused<<<dim3(NTOK), dim3(256), 0, stream>>>(
      C1, src, nullptr, n1_g, n1_b, nullptr, nullptr, x1b, 1, 0);

  // ---- cross-attention
  gemm256p<3, 1><<<dim3(64, 4), dim3(512), 0, stream>>>(
      x1b, wcaiw, ca_in_b, 1024, nullptr, 0, Qr, nullptr, nullptr, 1024);      // all -> Q
  gemm256p<3, 1><<<dim3(64, 4), dim3(512), 0, stream>>>(
      audb, wcaiw + (size_t)1024 * D_MODEL, ca_in_b + 1024, 1024,
      nullptr, 0, nullptr, Kr, nullptr, 0);                                    // all -> K
  gemm256p<2, 0><<<dim3(64, 4), dim3(512), 0, stream>>>(
      audb, wcaiw + (size_t)2048 * D_MODEL, ca_in_b + 2048, 1024,
      nullptr, 0, nullptr, nullptr, Vt, 0);
  attn_fused8<1><<<dim3(TM_ / 128, BATCH * NHEAD), dim3(512), 0, stream>>>(Qr, Kr, Vt, biasT, Orow);
  gemm256p<0, 1><<<dim3(64, 4), dim3(512), 0, stream>>>(
      Orow, wcaow, ca_out_b, 1024, C1, 1024, nullptr, nullptr, nullptr, 0);
  ln_fused<<<dim3(NTOK), dim3(256), 0, stream>>>(
      C1, nullptr, x1b, nc_g, nc_b, gate, nullptr, x2b, 0, 0);

  // ---- FFN
  gemm256p<1, 1><<<dim3(64, 16), dim3(512), 0, stream>>>(
      x2b, wl1, l1_b, 1024, H1, DFF_, nullptr, nullptr, nullptr, 0);
  gemm256p<0, 1><<<dim3(64, 4), dim3(512), 0, stream>>>(
      H1, wl2, l2_b, DFF_, C2, 1024, nullptr, nullptr, nullptr, 0);
  ln_fused<<<dim3(NTOK), dim3(256), 0, stream>>>(
      C2, nullptr, x2b, n2_g, n2_b, nullptr, out, nullptr, 0, 1);
}

// Round 16
// 946.252 us; speedup vs baseline: 1.2640x; 1.0656x over previous
//
#include <hip/hip_runtime.h>
#include <hip/hip_bf16.h>

#define D_MODEL 1024
#define NHEAD   16
#define HDIM    64
#define DFF_    4096
#define TM_     512
#define TA_     512
#define BATCH   32
#define NTOK    (TM_ * BATCH)   // 16384 tokens
#define NBEATS_ 64

typedef __bf16 bfv8 __attribute__((ext_vector_type(8)));
typedef float  f32x4 __attribute__((ext_vector_type(4)));
typedef unsigned short u16x8 __attribute__((ext_vector_type(8)));
typedef unsigned short u16x4 __attribute__((ext_vector_type(4)));

__device__ __forceinline__ unsigned short f2bf(float f) {
  union { float f; unsigned u; } v; v.f = f;
  unsigned r = v.u + 0x7fffu + ((v.u >> 16) & 1u);   // RNE
  return (unsigned short)(r >> 16);
}
__device__ __forceinline__ float bf2f(unsigned short h) {
  union { unsigned u; float f; } v; v.u = ((unsigned)h) << 16;
  return v.f;
}
// packed bf16 pair (compiler emits v_cvt_pk_bf16_f32)
__device__ __forceinline__ unsigned pk2bf(float a, float b) {
  __hip_bfloat162 t = __float22bfloat162_rn(make_float2(a, b));
  union { __hip_bfloat162 h; unsigned u; } v; v.h = t;
  return v.u;
}
// fast GELU (tanh form): th = 1 - 2/(e^{2u}+1); limits correct at +-inf.
__device__ __forceinline__ float gelu_fast(float v) {
  float t = v * v;
  float e = __expf(v * fmaf(0.0713554f, t, 1.5957691f));   // e^{2u}
  float r = __builtin_amdgcn_rcpf(e + 1.0f);
  return v - v * r;                                        // v*(1-r) = 0.5v(1+th)
}

// direct-to-LDS 16B async copy (per-lane global addr, wave-uniform LDS base + lane*16)
#define GLOAD_LDS16(g, l) __builtin_amdgcn_global_load_lds( \
    (const __attribute__((address_space(1))) unsigned int*)(g), \
    (__attribute__((address_space(3))) unsigned int*)(l), 16, 0, 0)

#define MEMFENCE asm volatile("" ::: "memory")
#define BARRIER  do { MEMFENCE; __builtin_amdgcn_s_barrier(); MEMFENCE; } while (0)

// ---------------------------------------------------------------- fallback (ws too small diagnostic)
__global__ __launch_bounds__(256) void copy_f32(const float* __restrict__ in, float* __restrict__ out) {
  long i = ((long)blockIdx.x * 256 + threadIdx.x) * 4;
  *(float4*)(out + i) = *(const float4*)(in + i);
}

// ---------------------------------------------------------------- converts
__global__ __launch_bounds__(256) void cvt_f32_bf16(
    const float* __restrict__ in, unsigned short* __restrict__ out) {
  long i = ((long)blockIdx.x * 256 + threadIdx.x) * 4;
  float4 v = *(const float4*)(in + i);
  u16x4 o = { f2bf(v.x), f2bf(v.y), f2bf(v.z), f2bf(v.w) };
  *(u16x4*)(out + i) = o;
}

// (t,b,d) f32 -> rows (b*512+t) bf16. blockIdx.x = input row (t*32+b).
__global__ __launch_bounds__(256) void cvt_remap_bt(
    const float* __restrict__ in, unsigned short* __restrict__ out) {
  long rin = blockIdx.x;
  int b = (int)(rin & 31), t = (int)(rin >> 5);
  long rout = (long)b * 512 + t;
  int c = threadIdx.x * 4;
  float4 v = *(const float4*)(in + rin * 1024 + c);
  u16x4 o = { f2bf(v.x), f2bf(v.y), f2bf(v.z), f2bf(v.w) };
  *(u16x4*)(out + rout * 1024 + c) = o;
}

// ---------------------------------------------------------------- bias precompute (NON-transposed: bias2d[tm][ta])
// After the v5 operand swap, the attn register axis is kv -> [q][kv] rows are float4-loadable.
__global__ __launch_bounds__(512) void build_bias(
    const int* __restrict__ beats, float* __restrict__ bias2d) {
  int tm = blockIdx.x;        // 512
  int ta = threadIdx.x;       // 512
  float m = 0.f;
  for (int i = 0; i < NBEATS_; ++i) {
    int bf = beats[i];
    if (bf == ta) m = fmaxf(m, 2.0f);
    if (bf > 0 && bf - 1 == ta) m = fmaxf(m, 1.0f);
    if (bf < TA_ - 1 && bf + 1 == ta) m = fmaxf(m, 1.0f);
  }
  float diff = (float)tm - (float)ta;   // scale = 1
  bias2d[(long)tm * TA_ + ta] = -(diff * diff) * (1.0f / 32.0f) + m;  // 2*sigma^2=32
}

// ---------------------------------------------------------------- GEMM 256x256 (round-12 verified, unchanged)
template<int EPI, int SWAP>
__global__ __launch_bounds__(512, 2) void gemm256p(
    const unsigned short* __restrict__ A, const unsigned short* __restrict__ Bw,
    const float* __restrict__ bias, int K,
    unsigned short* __restrict__ outP, int ldc,
    unsigned short* __restrict__ dq, unsigned short* __restrict__ dk,
    unsigned short* __restrict__ dv, int s1) {
  __shared__ __align__(16) unsigned short As[2][2][128 * 64];  // 64 KB
  __shared__ __align__(16) unsigned short Bs[2][2][128 * 64];  // 64 KB
  const int tid = threadIdx.x;
  const int w = tid >> 6, lane = tid & 63;
  const int l15 = lane & 15, l4 = lane >> 4;
  const int wm = w >> 2, wn = w & 3;            // 2 x 4 wave grid
  const long m0 = (long)blockIdx.x * 256;
  const long n0 = (long)blockIdx.y * 256;
  const int srow8 = lane >> 3;                  // dest row within 8-row slab
  const int scol = ((lane & 7) ^ srow8) * 8;    // pre-swizzled source col (elems)

  const unsigned short* bA00 = A  + (m0 +       (w * 2 + 0) * 8 + srow8) * (long)K + scol;
  const unsigned short* bA01 = A  + (m0 +       (w * 2 + 1) * 8 + srow8) * (long)K + scol;
  const unsigned short* bA10 = A  + (m0 + 128 + (w * 2 + 0) * 8 + srow8) * (long)K + scol;
  const unsigned short* bA11 = A  + (m0 + 128 + (w * 2 + 1) * 8 + srow8) * (long)K + scol;
  const unsigned short* bB00 = Bw + (n0 +       (w * 2 + 0) * 8 + srow8) * (long)K + scol;
  const unsigned short* bB01 = Bw + (n0 +       (w * 2 + 1) * 8 + srow8) * (long)K + scol;
  const unsigned short* bB10 = Bw + (n0 + 128 + (w * 2 + 0) * 8 + srow8) * (long)K + scol;
  const unsigned short* bB11 = Bw + (n0 + 128 + (w * 2 + 1) * 8 + srow8) * (long)K + scol;

  auto stA = [&](int kt, int h, const unsigned short* p0, const unsigned short* p1) {
    const int db = kt & 1;
    const long ko = (long)kt * 64;
    GLOAD_LDS16(p0 + ko, &As[db][h][(w * 2 + 0) * 512]);
    GLOAD_LDS16(p1 + ko, &As[db][h][(w * 2 + 1) * 512]);
  };
  auto stB = [&](int kt, int h, const unsigned short* p0, const unsigned short* p1) {
    const int db = kt & 1;
    const long ko = (long)kt * 64;
    GLOAD_LDS16(p0 + ko, &Bs[db][h][(w * 2 + 0) * 512]);
    GLOAD_LDS16(p1 + ko, &Bs[db][h][(w * 2 + 1) * 512]);
  };
  const int swzb0 = ((l4)     ^ (l15 & 7)) << 4;   // byte offset, kk=0
  const int swzb1 = ((l4 + 4) ^ (l15 & 7)) << 4;   // byte offset, kk=1
  auto rdfrag = [&](const unsigned short* buf, int r, int kk) -> bfv8 {
    return *(const bfv8*)((const char*)buf + r * 128 + (kk ? swzb1 : swzb0));
  };

  f32x4 acc[8][4] = {};
  bfv8 aF[4][2], bF[4][2];
  const int nt = K >> 6;
  const int hB = wn >> 1, rB0 = (wn & 1) * 64;

  stA(0, 0, bA00, bA01); stA(0, 1, bA10, bA11);
  stB(0, 0, bB00, bB01); stB(0, 1, bB10, bB11);
  stB(1, 0, bB00, bB01); stB(1, 1, bB10, bB11);
  stA(1, 0, bA00, bA01); stA(1, 1, bA10, bA11);
  asm volatile("s_waitcnt vmcnt(8)" ::: "memory");
  BARRIER;

  for (int t = 0; t < nt; ++t) {
    const int db = t & 1;
    const unsigned short* Ah = &As[db][wm][0];
    const unsigned short* Bh = &Bs[db][hB][0];
    const bool pf2 = (t + 2 < nt);

    // phase 0
#pragma unroll
    for (int mf = 0; mf < 4; ++mf) {
      aF[mf][0] = rdfrag(Ah, mf * 16 + l15, 0);
      aF[mf][1] = rdfrag(Ah, mf * 16 + l15, 1);
    }
#pragma unroll
    for (int nf = 0; nf < 2; ++nf) {
      bF[nf][0] = rdfrag(Bh, rB0 + nf * 16 + l15, 0);
      bF[nf][1] = rdfrag(Bh, rB0 + nf * 16 + l15, 1);
    }
    BARRIER;
    asm volatile("s_waitcnt lgkmcnt(0)" ::: "memory");
    __builtin_amdgcn_s_setprio(1);
#pragma unroll
    for (int mf = 0; mf < 4; ++mf)
#pragma unroll
      for (int nf = 0; nf < 2; ++nf)
#pragma unroll
        for (int kk = 0; kk < 2; ++kk)
          acc[mf][nf] = SWAP
            ? __builtin_amdgcn_mfma_f32_16x16x32_bf16(bF[nf][kk], aF[mf][kk], acc[mf][nf], 0, 0, 0)
            : __builtin_amdgcn_mfma_f32_16x16x32_bf16(aF[mf][kk], bF[nf][kk], acc[mf][nf], 0, 0, 0);
    __builtin_amdgcn_s_setprio(0);
    BARRIER;

    // phase 1
#pragma unroll
    for (int nf = 2; nf < 4; ++nf) {
      bF[nf][0] = rdfrag(Bh, rB0 + nf * 16 + l15, 0);
      bF[nf][1] = rdfrag(Bh, rB0 + nf * 16 + l15, 1);
    }
    BARRIER;
    asm volatile("s_waitcnt lgkmcnt(0)" ::: "memory");
    __builtin_amdgcn_s_setprio(1);
#pragma unroll
    for (int mf = 0; mf < 4; ++mf)
#pragma unroll
      for (int nf = 2; nf < 4; ++nf)
#pragma unroll
        for (int kk = 0; kk < 2; ++kk)
          acc[mf][nf] = SWAP
            ? __builtin_amdgcn_mfma_f32_16x16x32_bf16(bF[nf][kk], aF[mf][kk], acc[mf][nf], 0, 0, 0)
            : __builtin_amdgcn_mfma_f32_16x16x32_bf16(aF[mf][kk], bF[nf][kk], acc[mf][nf], 0, 0, 0);
    __builtin_amdgcn_s_setprio(0);
    BARRIER;

    // phase 2 (+ stage B(t+2))
#pragma unroll
    for (int mf = 0; mf < 4; ++mf) {
      aF[mf][0] = rdfrag(Ah, (mf + 4) * 16 + l15, 0);
      aF[mf][1] = rdfrag(Ah, (mf + 4) * 16 + l15, 1);
    }
    if (pf2) { stB(t + 2, 0, bB00, bB01); stB(t + 2, 1, bB10, bB11); }
    BARRIER;
    asm volatile("s_waitcnt lgkmcnt(0)" ::: "memory");
    __builtin_amdgcn_s_setprio(1);
#pragma unroll
    for (int mf = 0; mf < 4; ++mf)
#pragma unroll
      for (int nf = 0; nf < 2; ++nf)
#pragma unroll
        for (int kk = 0; kk < 2; ++kk)
          acc[mf + 4][nf] = SWAP
            ? __builtin_amdgcn_mfma_f32_16x16x32_bf16(bF[nf][kk], aF[mf][kk], acc[mf + 4][nf], 0, 0, 0)
            : __builtin_amdgcn_mfma_f32_16x16x32_bf16(aF[mf][kk], bF[nf][kk], acc[mf + 4][nf], 0, 0, 0);
    __builtin_amdgcn_s_setprio(0);
    BARRIER;

    // phase 3 (+ stage A(t+2), counted drain of t+1)
    if (pf2) { stA(t + 2, 0, bA00, bA01); stA(t + 2, 1, bA10, bA11); }
    __builtin_amdgcn_s_setprio(1);
#pragma unroll
    for (int mf = 0; mf < 4; ++mf)
#pragma unroll
      for (int nf = 2; nf < 4; ++nf)
#pragma unroll
        for (int kk = 0; kk < 2; ++kk)
          acc[mf + 4][nf] = SWAP
            ? __builtin_amdgcn_mfma_f32_16x16x32_bf16(bF[nf][kk], aF[mf][kk], acc[mf + 4][nf], 0, 0, 0)
            : __builtin_amdgcn_mfma_f32_16x16x32_bf16(aF[mf][kk], bF[nf][kk], acc[mf + 4][nf], 0, 0, 0);
    __builtin_amdgcn_s_setprio(0);
    if (pf2)                asm volatile("s_waitcnt vmcnt(8)" ::: "memory");
    else if (t + 1 < nt)    asm volatile("s_waitcnt vmcnt(0)" ::: "memory");
    BARRIER;
  }

  // epilogue (verified mappings)
#pragma unroll
  for (int mf = 0; mf < 8; ++mf)
#pragma unroll
    for (int nf = 0; nf < 4; ++nf) {
      if (SWAP) {
        const int mrow = (int)m0 + wm * 128 + mf * 16 + l15;
        const int col0 = (int)n0 + wn * 64 + nf * 16 + l4 * 4;
        float4 bv = bias ? *(const float4*)&bias[col0] : make_float4(0.f, 0.f, 0.f, 0.f);
        float v0 = acc[mf][nf][0] + bv.x, v1 = acc[mf][nf][1] + bv.y;
        float v2 = acc[mf][nf][2] + bv.z, v3 = acc[mf][nf][3] + bv.w;
        if (EPI == 1) { v0 = gelu_fast(v0); v1 = gelu_fast(v1); v2 = gelu_fast(v2); v3 = gelu_fast(v3); }
        if (EPI == 0 || EPI == 1) {
          uint2 ov; ov.x = pk2bf(v0, v1); ov.y = pk2bf(v2, v3);
          *(uint2*)&outP[(long)mrow * ldc + col0] = ov;
        } else {
          int b_ = mrow >> 9, t_ = mrow & 511;
          if (col0 < s1) {
            int h = col0 >> 6, d0 = col0 & 63;
            uint2 ov; ov.x = pk2bf(v0 * 0.125f, v1 * 0.125f); ov.y = pk2bf(v2 * 0.125f, v3 * 0.125f);
            *(uint2*)&dq[(((long)b_ * NHEAD + h) * TM_ + t_) * HDIM + d0] = ov;
          } else {
            int c0 = col0 - s1, h = c0 >> 6, d0 = c0 & 63;
            uint2 ov; ov.x = pk2bf(v0, v1); ov.y = pk2bf(v2, v3);
            *(uint2*)&dk[(((long)b_ * NHEAD + h) * TA_ + t_) * HDIM + d0] = ov;
          }
        }
      } else {
        const int col = (int)n0 + wn * 64 + nf * 16 + l15;
        const int row0 = (int)m0 + wm * 128 + mf * 16 + l4 * 4;
        float bv = bias ? bias[col] : 0.f;
        int b_ = row0 >> 9, t0 = row0 & 511;
        int h = col >> 6, d = col & 63;
        uint2 ov;
        ov.x = pk2bf(acc[mf][nf][0] + bv, acc[mf][nf][1] + bv);
        ov.y = pk2bf(acc[mf][nf][2] + bv, acc[mf][nf][3] + bv);
        *(uint2*)&dv[(((long)b_ * NHEAD + h) * HDIM + d) * TA_ + t0] = ov;
      }
    }
}

// ---------------------------------------------------------------- fused attention v9
// v8 math (verified) with counted-wait pipeline: 3-ring K/V buffers, ONE raw
// barrier + vmcnt(2) per tile (drains exactly tile t's 2 loads; t+1's stay in
// flight). stage(t+2) issued after the barrier (WAR-safe: buf (t+2)%3 == (t-1)%3,
// whose readers all passed this barrier). Bias loaded as float4 (non-transposed
// bias2d[q][kv]; kv is the register axis since the v5 swap).
template<int BIAS>
__global__ __launch_bounds__(512) void attn_fused9(
    const unsigned short* __restrict__ Qr, const unsigned short* __restrict__ Kr,
    const unsigned short* __restrict__ Vt, const float* __restrict__ bias2d,
    unsigned short* __restrict__ Orow) {
  __shared__ __align__(16) unsigned short Kb[3][64 * 64];     // 24 KB
  __shared__ __align__(16) unsigned short Vb[3][64 * 64];     // 24 KB
  __shared__ __align__(16) unsigned short P_lds[8][16][64];   // 16 KB
  const int flat = blockIdx.y * 4 + blockIdx.x;     // gridDim.x == 4, 2048 blocks
  const int W = (flat & 7) * 256 + (flat >> 3);     // XCD-chunked (bijective)
  const int bh = W >> 2;
  const int b = bh >> 4, h = bh & 15;
  const int tid = threadIdx.x, w = tid >> 6, lane = tid & 63;   // w in 0..7
  const int l15 = lane & 15, l4 = lane >> 4;
  const int q0 = (W & 3) * 128 + w * 16;            // this wave's 16 q rows

  const unsigned short* Kg = Kr + (long)bh * TA_ * HDIM;
  const unsigned short* Vg = Vt + (long)bh * HDIM * TA_;

  const int stg_row = lane >> 3;                    // row within wave's 8-row slab
  const int stg_col = ((lane & 7) ^ stg_row) * 8;   // pre-swizzled source col

  auto stage = [&](int t, int cb) {                 // wave w stages rows w*8..w*8+7 of K and V
    const int kv0 = t * 64;
    int row = w * 8 + stg_row;
    GLOAD_LDS16(Kg + (long)(kv0 + row) * HDIM + stg_col, &Kb[cb][(w * 8) * 64]);
    GLOAD_LDS16(Vg + (long)row * TA_ + kv0 + stg_col,    &Vb[cb][(w * 8) * 64]);
  };

  bfv8 qf[2];
#pragma unroll
  for (int kc = 0; kc < 2; ++kc)
    qf[kc] = *(const bfv8*)&Qr[((long)bh * TM_ + q0 + l15) * HDIM + kc * 32 + l4 * 8];

  float mrun = -1e30f, lrun = 0.f;
  f32x4 o[4] = {};   // o[fd] = O^T[d][q=l15]
  unsigned short* prow = &P_lds[w][l15][0];
  const int swz = (l15 & 7) * 8;
  const float* biasrow = BIAS ? &bias2d[(long)(q0 + l15) * TA_] : nullptr;

  stage(0, 0);
  stage(1, 1);

  for (int t = 0; t < 8; ++t) {
    // counted drain: tile t's 2 loads are the oldest; t+1's (if any) stay in flight
    if (t < 7) asm volatile("s_waitcnt vmcnt(2)" ::: "memory");
    else       asm volatile("s_waitcnt vmcnt(0)" ::: "memory");
    BARRIER;                                       // publishes tile t; all waves past PV(t-1)
    if (t + 2 < 8) stage(t + 2, (t + 2) % 3);      // writes buf (t-1)%3 — readers done
    const int cur = t % 3;
    const int kv0 = t * 64;
    // ---- QK^T from staged K
    f32x4 s[4] = {};
#pragma unroll
    for (int f = 0; f < 4; ++f) {
#pragma unroll
      for (int kc = 0; kc < 2; ++kc) {
        bfv8 kf = *(const bfv8*)&Kb[cur][(f * 16 + l15) * 64 + (((kc * 4 + l4) * 8) ^ swz)];
        s[f] = __builtin_amdgcn_mfma_f32_16x16x32_bf16(kf, qf[kc], s[f], 0, 0, 0);
      }
    }
    if (BIAS) {
#pragma unroll
      for (int f = 0; f < 4; ++f) {
        float4 bv = *(const float4*)&biasrow[kv0 + f * 16 + l4 * 4];
        s[f][0] += bv.x; s[f][1] += bv.y; s[f][2] += bv.z; s[f][3] += bv.w;
      }
    }
    // ---- tile max (tree; fuses to v_max3) + wave halves
    float t0 = fmaxf(fmaxf(s[0][0], s[0][1]), fmaxf(s[0][2], s[0][3]));
    float t1 = fmaxf(fmaxf(s[1][0], s[1][1]), fmaxf(s[1][2], s[1][3]));
    float t2 = fmaxf(fmaxf(s[2][0], s[2][1]), fmaxf(s[2][2], s[2][3]));
    float t3 = fmaxf(fmaxf(s[3][0], s[3][1]), fmaxf(s[3][2], s[3][3]));
    float pmax = fmaxf(fmaxf(t0, t1), fmaxf(t2, t3));
    pmax = fmaxf(pmax, __shfl_xor(pmax, 16));
    pmax = fmaxf(pmax, __shfl_xor(pmax, 32));
    // ---- defer-max (T13): only rescale when max grew past THR=8
    if (!__all(pmax - mrun <= 8.0f)) {
      float newm = fmaxf(mrun, pmax);
      float corr = __expf(mrun - newm);   // row q=l15 == O's lane row: direct rescale
      lrun *= corr;
#pragma unroll
      for (int fd = 0; fd < 4; ++fd)
#pragma unroll
        for (int r = 0; r < 4; ++r) o[fd][r] *= corr;
      mrun = newm;
    }
    // ---- exp (bounded by e^8) + pack/write P + psum tree
    float p0 = 0.f, p1 = 0.f, p2 = 0.f, p3 = 0.f;
#pragma unroll
    for (int f = 0; f < 4; ++f) {
      float e0 = __expf(s[f][0] - mrun), e1 = __expf(s[f][1] - mrun);
      float e2 = __expf(s[f][2] - mrun), e3 = __expf(s[f][3] - mrun);
      p0 += e0; p1 += e1; p2 += e2; p3 += e3;
      unsigned w0 = pk2bf(e0, e1);
      unsigned w1 = pk2bf(e2, e3);
      int blkW = ((f << 1) | (l4 >> 1)) ^ (l15 & 7);
      uint2 pw; pw.x = w0; pw.y = w1;
      *(uint2*)((char*)prow + blkW * 16 + (l4 & 1) * 8) = pw;
    }
    float psum = (p0 + p1) + (p2 + p3);
    psum += __shfl_xor(psum, 16);
    psum += __shfl_xor(psum, 32);
    lrun += psum;
    asm volatile("s_waitcnt lgkmcnt(0)" ::: "memory");
    __builtin_amdgcn_sched_barrier(0);   // rule #18
    // ---- PV from staged V (swapped -> O rows lane-local)
#pragma unroll
    for (int c = 0; c < 2; ++c) {
      int blkR = ((c << 2) | l4) ^ (l15 & 7);
      bfv8 pa = *(const bfv8*)((const char*)prow + blkR * 16);
#pragma unroll
      for (int fd = 0; fd < 4; ++fd) {
        bfv8 vb = *(const bfv8*)&Vb[cur][(fd * 16 + l15) * 64 + (((c * 4 + l4) * 8) ^ swz)];
        o[fd] = __builtin_amdgcn_mfma_f32_16x16x32_bf16(vb, pa, o[fd], 0, 0, 0);  // swapped
      }
    }
    // no end-of-tile barrier: next iteration's top barrier covers WAR + visibility
  }

  float invl = 1.f / lrun;
  const long obase = ((long)b * 512 + q0 + l15) * D_MODEL + h * HDIM;
#pragma unroll
  for (int fd = 0; fd < 4; ++fd) {
    uint2 ov;
    ov.x = pk2bf(o[fd][0] * invl, o[fd][1] * invl);
    ov.y = pk2bf(o[fd][2] * invl, o[fd][3] * invl);
    *(uint2*)&Orow[obase + fd * 16 + l4 * 4] = ov;
  }
}

// ---------------------------------------------------------------- fused residual + LayerNorm
__global__ __launch_bounds__(256) void ln_fused(
    const unsigned short* __restrict__ cin,
    const float* __restrict__ residf, const unsigned short* __restrict__ residb,
    const float* __restrict__ gamma, const float* __restrict__ beta,
    const float* __restrict__ gate,
    float* __restrict__ out_f32, unsigned short* __restrict__ out_bf16,
    int remap_resid, int remap_out) {
  long row = blockIdx.x;
  int t = threadIdx.x;
  int tt = (int)(row & 511), bb = (int)(row >> 9);
  long row_tb = (long)tt * 32 + bb;
  float gf = gate ? tanhf(gate[0]) : 1.0f;
  u16x4 cvb = *(const u16x4*)(cin + row * 1024 + t * 4);
  float c0 = bf2f(cvb[0]), c1 = bf2f(cvb[1]), c2 = bf2f(cvb[2]), c3 = bf2f(cvb[3]);
  float r0, r1, r2, r3;
  if (residf) {
    long rr = remap_resid ? row_tb : row;
    float4 rv = *(const float4*)(residf + rr * 1024 + t * 4);
    r0 = rv.x; r1 = rv.y; r2 = rv.z; r3 = rv.w;
  } else {
    u16x4 rv = *(const u16x4*)(residb + row * 1024 + t * 4);
    r0 = bf2f(rv[0]); r1 = bf2f(rv[1]); r2 = bf2f(rv[2]); r3 = bf2f(rv[3]);
  }
  float y0 = r0 + gf * c0, y1 = r1 + gf * c1, y2 = r2 + gf * c2, y3 = r3 + gf * c3;
  float s = y0 + y1 + y2 + y3;
  float q = y0 * y0 + y1 * y1 + y2 * y2 + y3 * y3;
#pragma unroll
  for (int off = 32; off; off >>= 1) { s += __shfl_xor(s, off); q += __shfl_xor(q, off); }
  __shared__ float sw[4], qw[4];
  int wave = t >> 6;
  if ((t & 63) == 0) { sw[wave] = s; qw[wave] = q; }
  __syncthreads();
  s = sw[0] + sw[1] + sw[2] + sw[3];
  q = qw[0] + qw[1] + qw[2] + qw[3];
  float mean = s * (1.0f / 1024.0f);
  float var = q * (1.0f / 1024.0f) - mean * mean;
  float rstd = rsqrtf(var + 1e-5f);
  float4 g4 = *(const float4*)(gamma + t * 4);
  float4 b4 = *(const float4*)(beta + t * 4);
  float o0 = (y0 - mean) * rstd * g4.x + b4.x;
  float o1 = (y1 - mean) * rstd * g4.y + b4.y;
  float o2 = (y2 - mean) * rstd * g4.z + b4.z;
  float o3 = (y3 - mean) * rstd * g4.w + b4.w;
  if (out_f32) {
    long ro = remap_out ? row_tb : row;
    float4 o = { o0, o1, o2, o3 };
    *(float4*)(out_f32 + ro * 1024 + t * 4) = o;
  }
  if (out_bf16) {
    u16x4 ob = { f2bf(o0), f2bf(o1), f2bf(o2), f2bf(o3) };
    *(u16x4*)(out_bf16 + row * 1024 + t * 4) = ob;
  }
}

// ---------------------------------------------------------------- host
static inline char* wsa(char*& p, size_t bytes) {
  char* r = p;
  p += (bytes + 255) & ~(size_t)255;
  return r;
}

extern "C" void kernel_launch(void* const* d_in, const int* in_sizes, int n_in,
                              void* d_out, int out_size, void* d_ws, size_t ws_size,
                              hipStream_t stream) {
  const float* src      = (const float*)d_in[0];
  const float* audio    = (const float*)d_in[1];
  const int*   beats    = (const int*)d_in[2];
  const float* sa_in_w  = (const float*)d_in[3];
  const float* sa_in_b  = (const float*)d_in[4];
  const float* sa_out_w = (const float*)d_in[5];
  const float* sa_out_b = (const float*)d_in[6];
  const float* ca_in_w  = (const float*)d_in[7];
  const float* ca_in_b  = (const float*)d_in[8];
  const float* ca_out_w = (const float*)d_in[9];
  const float* ca_out_b = (const float*)d_in[10];
  const float* gate     = (const float*)d_in[11];
  const float* n1_g     = (const float*)d_in[12];
  const float* n1_b     = (const float*)d_in[13];
  const float* nc_g     = (const float*)d_in[14];
  const float* nc_b     = (const float*)d_in[15];
  const float* n2_g     = (const float*)d_in[16];
  const float* n2_b     = (const float*)d_in[17];
  const float* l1_w     = (const float*)d_in[18];
  const float* l1_b     = (const float*)d_in[19];
  const float* l2_w     = (const float*)d_in[20];
  const float* l2_b     = (const float*)d_in[21];
  float* out = (float*)d_out;
  (void)in_sizes; (void)n_in; (void)out_size;

  const size_t NEEDED = (size_t)236000000;
  if (ws_size < NEEDED) {
    copy_f32<<<dim3(NTOK), dim3(256), 0, stream>>>(src, out);
    return;
  }

  char* p = (char*)d_ws;
  float*          bias2d = (float*)         wsa(p, (size_t)TM_ * TA_ * 4);
  unsigned short* wsaiw  = (unsigned short*)wsa(p, (size_t)3 * D_MODEL * D_MODEL * 2);
  unsigned short* wsaow  = (unsigned short*)wsa(p, (size_t)D_MODEL * D_MODEL * 2);
  unsigned short* wcaiw  = (unsigned short*)wsa(p, (size_t)3 * D_MODEL * D_MODEL * 2);
  unsigned short* wcaow  = (unsigned short*)wsa(p, (size_t)D_MODEL * D_MODEL * 2);
  unsigned short* wl1    = (unsigned short*)wsa(p, (size_t)DFF_ * D_MODEL * 2);
  unsigned short* wl2    = (unsigned short*)wsa(p, (size_t)D_MODEL * DFF_ * 2);
  unsigned short* srcb   = (unsigned short*)wsa(p, (size_t)NTOK * D_MODEL * 2);
  unsigned short* audb   = (unsigned short*)wsa(p, (size_t)NTOK * D_MODEL * 2);
  // H1 (128 MiB) overlays [Qr | Kr | Vt | x1b]:
  unsigned short* Qr     = (unsigned short*)wsa(p, (size_t)NTOK * D_MODEL * 2);
  unsigned short* Kr     = (unsigned short*)wsa(p, (size_t)NTOK * D_MODEL * 2);
  unsigned short* Vt     = (unsigned short*)wsa(p, (size_t)NTOK * D_MODEL * 2);
  unsigned short* x1b    = (unsigned short*)wsa(p, (size_t)NTOK * D_MODEL * 2);
  unsigned short* Orow   = srcb;
  unsigned short* C1     = Vt;
  unsigned short* x2b    = audb;
  unsigned short* H1     = Qr;
  unsigned short* C2     = srcb;

  // ---- bias + converts
  build_bias<<<dim3(TM_), dim3(TA_), 0, stream>>>(beats, bias2d);
  cvt_remap_bt<<<dim3(NTOK), dim3(256), 0, stream>>>(src, srcb);
  cvt_remap_bt<<<dim3(NTOK), dim3(256), 0, stream>>>(audio, audb);
  cvt_f32_bf16<<<dim3((3 * D_MODEL * D_MODEL) / 1024), dim3(256), 0, stream>>>(sa_in_w, wsaiw);
  cvt_f32_bf16<<<dim3((D_MODEL * D_MODEL) / 1024), dim3(256), 0, stream>>>(sa_out_w, wsaow);
  cvt_f32_bf16<<<dim3((3 * D_MODEL * D_MODEL) / 1024), dim3(256), 0, stream>>>(ca_in_w, wcaiw);
  cvt_f32_bf16<<<dim3((D_MODEL * D_MODEL) / 1024), dim3(256), 0, stream>>>(ca_out_w, wcaow);
  cvt_f32_bf16<<<dim3((DFF_ * D_MODEL) / 1024), dim3(256), 0, stream>>>(l1_w, wl1);
  cvt_f32_bf16<<<dim3((D_MODEL * DFF_) / 1024), dim3(256), 0, stream>>>(l2_w, wl2);

  // ---- self-attention
  gemm256p<3, 1><<<dim3(64, 8), dim3(512), 0, stream>>>(
      srcb, wsaiw, sa_in_b, 1024, nullptr, 0, Qr, Kr, nullptr, 1024);
  gemm256p<2, 0><<<dim3(64, 4), dim3(512), 0, stream>>>(
      srcb, wsaiw + (size_t)2048 * D_MODEL, sa_in_b + 2048, 1024,
      nullptr, 0, nullptr, nullptr, Vt, 0);
  attn_fused9<0><<<dim3(TM_ / 128, BATCH * NHEAD), dim3(512), 0, stream>>>(Qr, Kr, Vt, nullptr, Orow);
  gemm256p<0, 1><<<dim3(64, 4), dim3(512), 0, stream>>>(
      Orow, wsaow, sa_out_b, 1024, C1, 1024, nullptr, nullptr, nullptr, 0);
  ln_fused<<<dim3(NTOK), dim3(256), 0, stream>>>(
      C1, src, nullptr, n1_g, n1_b, nullptr, nullptr, x1b, 1, 0);

  // ---- cross-attention
  gemm256p<3, 1><<<dim3(64, 4), dim3(512), 0, stream>>>(
      x1b, wcaiw, ca_in_b, 1024, nullptr, 0, Qr, nullptr, nullptr, 1024);      // all -> Q
  gemm256p<3, 1><<<dim3(64, 4), dim3(512), 0, stream>>>(
      audb, wcaiw + (size_t)1024 * D_MODEL, ca_in_b + 1024, 1024,
      nullptr, 0, nullptr, Kr, nullptr, 0);                                    // all -> K
  gemm256p<2, 0><<<dim3(64, 4), dim3(512), 0, stream>>>(
      audb, wcaiw + (size_t)2048 * D_MODEL, ca_in_b + 2048, 1024,
      nullptr, 0, nullptr, nullptr, Vt, 0);
  attn_fused9<1><<<dim3(TM_ / 128, BATCH * NHEAD), dim3(512), 0, stream>>>(Qr, Kr, Vt, bias2d, Orow);
  gemm256p<0, 1><<<dim3(64, 4), dim3(512), 0, stream>>>(
      Orow, wcaow, ca_out_b, 1024, C1, 1024, nullptr, nullptr, nullptr, 0);
  ln_fused<<<dim3(NTOK), dim3(256), 0, stream>>>(
      C1, nullptr, x1b, nc_g, nc_b, gate, nullptr, x2b, 0, 0);

  // ---- FFN
  gemm256p<1, 1><<<dim3(64, 16), dim3(512), 0, stream>>>(
      x2b, wl1, l1_b, 1024, H1, DFF_, nullptr, nullptr, nullptr, 0);
  gemm256p<0, 1><<<dim3(64, 4), dim3(512), 0, stream>>>(
      H1, wl2, l2_b, DFF_, C2, 1024, nullptr, nullptr, nullptr, 0);
  ln_fused<<<dim3(NTOK), dim3(256), 0, stream>>>(
      C2, nullptr, x2b, n2_g, n2_b, nullptr, out, nullptr, 0, 1);
}

// Round 18
// 936.996 us; speedup vs baseline: 1.2765x; 1.0099x over previous
//
#include <hip/hip_runtime.h>
#include <hip/hip_bf16.h>

#define D_MODEL 1024
#define NHEAD   16
#define HDIM    64
#define DFF_    4096
#define TM_     512
#define TA_     512
#define BATCH   32
#define NTOK    (TM_ * BATCH)   // 16384 tokens
#define NBEATS_ 64

typedef __bf16 bfv8 __attribute__((ext_vector_type(8)));
typedef float  f32x4 __attribute__((ext_vector_type(4)));
typedef unsigned short u16x8 __attribute__((ext_vector_type(8)));
typedef unsigned short u16x4 __attribute__((ext_vector_type(4)));

__device__ __forceinline__ unsigned short f2bf(float f) {
  union { float f; unsigned u; } v; v.f = f;
  unsigned r = v.u + 0x7fffu + ((v.u >> 16) & 1u);   // RNE
  return (unsigned short)(r >> 16);
}
__device__ __forceinline__ float bf2f(unsigned short h) {
  union { unsigned u; float f; } v; v.u = ((unsigned)h) << 16;
  return v.f;
}
// packed bf16 pair (compiler emits v_cvt_pk_bf16_f32)
__device__ __forceinline__ unsigned pk2bf(float a, float b) {
  __hip_bfloat162 t = __float22bfloat162_rn(make_float2(a, b));
  union { __hip_bfloat162 h; unsigned u; } v; v.h = t;
  return v.u;
}
// fast GELU (tanh form): th = 1 - 2/(e^{2u}+1); limits correct at +-inf.
__device__ __forceinline__ float gelu_fast(float v) {
  float t = v * v;
  float e = __expf(v * fmaf(0.0713554f, t, 1.5957691f));   // e^{2u}
  float r = __builtin_amdgcn_rcpf(e + 1.0f);
  return v - v * r;                                        // v*(1-r) = 0.5v(1+th)
}

// direct-to-LDS 16B async copy (per-lane global addr, wave-uniform LDS base + lane*16)
#define GLOAD_LDS16(g, l) __builtin_amdgcn_global_load_lds( \
    (const __attribute__((address_space(1))) unsigned int*)(g), \
    (__attribute__((address_space(3))) unsigned int*)(l), 16, 0, 0)

#define MEMFENCE asm volatile("" ::: "memory")
#define BARRIER  do { MEMFENCE; __builtin_amdgcn_s_barrier(); MEMFENCE; } while (0)

// ---------------------------------------------------------------- fallback (ws too small diagnostic)
__global__ __launch_bounds__(256) void copy_f32(const float* __restrict__ in, float* __restrict__ out) {
  long i = ((long)blockIdx.x * 256 + threadIdx.x) * 4;
  *(float4*)(out + i) = *(const float4*)(in + i);
}

// ---------------------------------------------------------------- converts (consolidated, standalone kernels)
// All 6 weight tensors in one segmented kernel. Boundaries (elems/4-blocks over flat idx).
__global__ __launch_bounds__(256) void cvt_weights(
    const float* __restrict__ w0, const float* __restrict__ w1,
    const float* __restrict__ w2, const float* __restrict__ w3,
    const float* __restrict__ w4, const float* __restrict__ w5,
    unsigned short* __restrict__ o0, unsigned short* __restrict__ o1,
    unsigned short* __restrict__ o2, unsigned short* __restrict__ o3,
    unsigned short* __restrict__ o4, unsigned short* __restrict__ o5) {
  long i4 = ((long)blockIdx.x * 256 + threadIdx.x) * 4;
  const float* src; unsigned short* dst; long off;
  if      (i4 <  3145728) { src = w0; dst = o0; off = i4; }
  else if (i4 <  4194304) { src = w1; dst = o1; off = i4 -  3145728; }
  else if (i4 <  7340032) { src = w2; dst = o2; off = i4 -  4194304; }
  else if (i4 <  8388608) { src = w3; dst = o3; off = i4 -  7340032; }
  else if (i4 < 12582912) { src = w4; dst = o4; off = i4 -  8388608; }
  else                    { src = w5; dst = o5; off = i4 - 12582912; }
  float4 v = *(const float4*)(src + off);
  u16x4 o = { f2bf(v.x), f2bf(v.y), f2bf(v.z), f2bf(v.w) };
  *(u16x4*)(dst + off) = o;
}

// (t,b,d) f32 -> rows (b*512+t) bf16, for src (y=0) and audio (y=1) in one launch.
__global__ __launch_bounds__(256) void cvt_remap2(
    const float* __restrict__ src, const float* __restrict__ audio,
    unsigned short* __restrict__ srcb, unsigned short* __restrict__ audb) {
  const float* in = blockIdx.y ? audio : src;
  unsigned short* out = blockIdx.y ? audb : srcb;
  long rin = blockIdx.x;
  int b = (int)(rin & 31), t = (int)(rin >> 5);
  long rout = (long)b * 512 + t;
  int c = threadIdx.x * 4;
  float4 v = *(const float4*)(in + rin * 1024 + c);
  u16x4 o = { f2bf(v.x), f2bf(v.y), f2bf(v.z), f2bf(v.w) };
  *(u16x4*)(out + rout * 1024 + c) = o;
}

// ---------------------------------------------------------------- bias precompute (bias2d[tm][ta])
__global__ __launch_bounds__(512) void build_bias(
    const int* __restrict__ beats, float* __restrict__ bias2d) {
  int tm = blockIdx.x;        // 512
  int ta = threadIdx.x;       // 512
  float m = 0.f;
  for (int i = 0; i < NBEATS_; ++i) {
    int bf = beats[i];
    if (bf == ta) m = fmaxf(m, 2.0f);
    if (bf > 0 && bf - 1 == ta) m = fmaxf(m, 1.0f);
    if (bf < TA_ - 1 && bf + 1 == ta) m = fmaxf(m, 1.0f);
  }
  float diff = (float)tm - (float)ta;   // scale = 1
  bias2d[(long)tm * TA_ + ta] = -(diff * diff) * (1.0f / 32.0f) + m;  // 2*sigma^2=32
}

// ---------------------------------------------------------------- GEMM 256x256 (round-16 verified, unchanged)
template<int EPI, int SWAP>
__global__ __launch_bounds__(512, 2) void gemm256p(
    const unsigned short* __restrict__ A, const unsigned short* __restrict__ Bw,
    const float* __restrict__ bias, int K,
    unsigned short* __restrict__ outP, int ldc,
    unsigned short* __restrict__ dq, unsigned short* __restrict__ dk,
    unsigned short* __restrict__ dv, int s1) {
  __shared__ __align__(16) unsigned short As[2][2][128 * 64];  // 64 KB
  __shared__ __align__(16) unsigned short Bs[2][2][128 * 64];  // 64 KB
  const int tid = threadIdx.x;
  const int w = tid >> 6, lane = tid & 63;
  const int l15 = lane & 15, l4 = lane >> 4;
  const int wm = w >> 2, wn = w & 3;            // 2 x 4 wave grid
  const long m0 = (long)blockIdx.x * 256;
  const long n0 = (long)blockIdx.y * 256;
  const int srow8 = lane >> 3;                  // dest row within 8-row slab
  const int scol = ((lane & 7) ^ srow8) * 8;    // pre-swizzled source col (elems)

  const unsigned short* bA00 = A  + (m0 +       (w * 2 + 0) * 8 + srow8) * (long)K + scol;
  const unsigned short* bA01 = A  + (m0 +       (w * 2 + 1) * 8 + srow8) * (long)K + scol;
  const unsigned short* bA10 = A  + (m0 + 128 + (w * 2 + 0) * 8 + srow8) * (long)K + scol;
  const unsigned short* bA11 = A  + (m0 + 128 + (w * 2 + 1) * 8 + srow8) * (long)K + scol;
  const unsigned short* bB00 = Bw + (n0 +       (w * 2 + 0) * 8 + srow8) * (long)K + scol;
  const unsigned short* bB01 = Bw + (n0 +       (w * 2 + 1) * 8 + srow8) * (long)K + scol;
  const unsigned short* bB10 = Bw + (n0 + 128 + (w * 2 + 0) * 8 + srow8) * (long)K + scol;
  const unsigned short* bB11 = Bw + (n0 + 128 + (w * 2 + 1) * 8 + srow8) * (long)K + scol;

  auto stA = [&](int kt, int h, const unsigned short* p0, const unsigned short* p1) {
    const int db = kt & 1;
    const long ko = (long)kt * 64;
    GLOAD_LDS16(p0 + ko, &As[db][h][(w * 2 + 0) * 512]);
    GLOAD_LDS16(p1 + ko, &As[db][h][(w * 2 + 1) * 512]);
  };
  auto stB = [&](int kt, int h, const unsigned short* p0, const unsigned short* p1) {
    const int db = kt & 1;
    const long ko = (long)kt * 64;
    GLOAD_LDS16(p0 + ko, &Bs[db][h][(w * 2 + 0) * 512]);
    GLOAD_LDS16(p1 + ko, &Bs[db][h][(w * 2 + 1) * 512]);
  };
  const int swzb0 = ((l4)     ^ (l15 & 7)) << 4;   // byte offset, kk=0
  const int swzb1 = ((l4 + 4) ^ (l15 & 7)) << 4;   // byte offset, kk=1
  auto rdfrag = [&](const unsigned short* buf, int r, int kk) -> bfv8 {
    return *(const bfv8*)((const char*)buf + r * 128 + (kk ? swzb1 : swzb0));
  };

  f32x4 acc[8][4] = {};
  bfv8 aF[4][2], bF[4][2];
  const int nt = K >> 6;
  const int hB = wn >> 1, rB0 = (wn & 1) * 64;

  stA(0, 0, bA00, bA01); stA(0, 1, bA10, bA11);
  stB(0, 0, bB00, bB01); stB(0, 1, bB10, bB11);
  stB(1, 0, bB00, bB01); stB(1, 1, bB10, bB11);
  stA(1, 0, bA00, bA01); stA(1, 1, bA10, bA11);
  asm volatile("s_waitcnt vmcnt(8)" ::: "memory");
  BARRIER;

  for (int t = 0; t < nt; ++t) {
    const int db = t & 1;
    const unsigned short* Ah = &As[db][wm][0];
    const unsigned short* Bh = &Bs[db][hB][0];
    const bool pf2 = (t + 2 < nt);

    // phase 0
#pragma unroll
    for (int mf = 0; mf < 4; ++mf) {
      aF[mf][0] = rdfrag(Ah, mf * 16 + l15, 0);
      aF[mf][1] = rdfrag(Ah, mf * 16 + l15, 1);
    }
#pragma unroll
    for (int nf = 0; nf < 2; ++nf) {
      bF[nf][0] = rdfrag(Bh, rB0 + nf * 16 + l15, 0);
      bF[nf][1] = rdfrag(Bh, rB0 + nf * 16 + l15, 1);
    }
    BARRIER;
    asm volatile("s_waitcnt lgkmcnt(0)" ::: "memory");
    __builtin_amdgcn_s_setprio(1);
#pragma unroll
    for (int mf = 0; mf < 4; ++mf)
#pragma unroll
      for (int nf = 0; nf < 2; ++nf)
#pragma unroll
        for (int kk = 0; kk < 2; ++kk)
          acc[mf][nf] = SWAP
            ? __builtin_amdgcn_mfma_f32_16x16x32_bf16(bF[nf][kk], aF[mf][kk], acc[mf][nf], 0, 0, 0)
            : __builtin_amdgcn_mfma_f32_16x16x32_bf16(aF[mf][kk], bF[nf][kk], acc[mf][nf], 0, 0, 0);
    __builtin_amdgcn_s_setprio(0);
    BARRIER;

    // phase 1
#pragma unroll
    for (int nf = 2; nf < 4; ++nf) {
      bF[nf][0] = rdfrag(Bh, rB0 + nf * 16 + l15, 0);
      bF[nf][1] = rdfrag(Bh, rB0 + nf * 16 + l15, 1);
    }
    BARRIER;
    asm volatile("s_waitcnt lgkmcnt(0)" ::: "memory");
    __builtin_amdgcn_s_setprio(1);
#pragma unroll
    for (int mf = 0; mf < 4; ++mf)
#pragma unroll
      for (int nf = 2; nf < 4; ++nf)
#pragma unroll
        for (int kk = 0; kk < 2; ++kk)
          acc[mf][nf] = SWAP
            ? __builtin_amdgcn_mfma_f32_16x16x32_bf16(bF[nf][kk], aF[mf][kk], acc[mf][nf], 0, 0, 0)
            : __builtin_amdgcn_mfma_f32_16x16x32_bf16(aF[mf][kk], bF[nf][kk], acc[mf][nf], 0, 0, 0);
    __builtin_amdgcn_s_setprio(0);
    BARRIER;

    // phase 2 (+ stage B(t+2))
#pragma unroll
    for (int mf = 0; mf < 4; ++mf) {
      aF[mf][0] = rdfrag(Ah, (mf + 4) * 16 + l15, 0);
      aF[mf][1] = rdfrag(Ah, (mf + 4) * 16 + l15, 1);
    }
    if (pf2) { stB(t + 2, 0, bB00, bB01); stB(t + 2, 1, bB10, bB11); }
    BARRIER;
    asm volatile("s_waitcnt lgkmcnt(0)" ::: "memory");
    __builtin_amdgcn_s_setprio(1);
#pragma unroll
    for (int mf = 0; mf < 4; ++mf)
#pragma unroll
      for (int nf = 0; nf < 2; ++nf)
#pragma unroll
        for (int kk = 0; kk < 2; ++kk)
          acc[mf + 4][nf] = SWAP
            ? __builtin_amdgcn_mfma_f32_16x16x32_bf16(bF[nf][kk], aF[mf][kk], acc[mf + 4][nf], 0, 0, 0)
            : __builtin_amdgcn_mfma_f32_16x16x32_bf16(aF[mf][kk], bF[nf][kk], acc[mf + 4][nf], 0, 0, 0);
    __builtin_amdgcn_s_setprio(0);
    BARRIER;

    // phase 3 (+ stage A(t+2), counted drain of t+1)
    if (pf2) { stA(t + 2, 0, bA00, bA01); stA(t + 2, 1, bA10, bA11); }
    __builtin_amdgcn_s_setprio(1);
#pragma unroll
    for (int mf = 0; mf < 4; ++mf)
#pragma unroll
      for (int nf = 2; nf < 4; ++nf)
#pragma unroll
        for (int kk = 0; kk < 2; ++kk)
          acc[mf + 4][nf] = SWAP
            ? __builtin_amdgcn_mfma_f32_16x16x32_bf16(bF[nf][kk], aF[mf][kk], acc[mf + 4][nf], 0, 0, 0)
            : __builtin_amdgcn_mfma_f32_16x16x32_bf16(aF[mf][kk], bF[nf][kk], acc[mf + 4][nf], 0, 0, 0);
    __builtin_amdgcn_s_setprio(0);
    if (pf2)                asm volatile("s_waitcnt vmcnt(8)" ::: "memory");
    else if (t + 1 < nt)    asm volatile("s_waitcnt vmcnt(0)" ::: "memory");
    BARRIER;
  }

  // epilogue (verified mappings)
#pragma unroll
  for (int mf = 0; mf < 8; ++mf)
#pragma unroll
    for (int nf = 0; nf < 4; ++nf) {
      if (SWAP) {
        const int mrow = (int)m0 + wm * 128 + mf * 16 + l15;
        const int col0 = (int)blockIdx.y * 256 + wn * 64 + nf * 16 + l4 * 4;
        float4 bv = bias ? *(const float4*)&bias[col0] : make_float4(0.f, 0.f, 0.f, 0.f);
        float v0 = acc[mf][nf][0] + bv.x, v1 = acc[mf][nf][1] + bv.y;
        float v2 = acc[mf][nf][2] + bv.z, v3 = acc[mf][nf][3] + bv.w;
        if (EPI == 1) { v0 = gelu_fast(v0); v1 = gelu_fast(v1); v2 = gelu_fast(v2); v3 = gelu_fast(v3); }
        if (EPI == 0 || EPI == 1) {
          uint2 ov; ov.x = pk2bf(v0, v1); ov.y = pk2bf(v2, v3);
          *(uint2*)&outP[(long)mrow * ldc + col0] = ov;
        } else {   // EPI == 3: Q/K scatter, d-contiguous
          int b_ = mrow >> 9, t_ = mrow & 511;
          if (col0 < s1) {
            int h = col0 >> 6, d0 = col0 & 63;
            uint2 ov; ov.x = pk2bf(v0 * 0.125f, v1 * 0.125f); ov.y = pk2bf(v2 * 0.125f, v3 * 0.125f);
            *(uint2*)&dq[(((long)b_ * NHEAD + h) * TM_ + t_) * HDIM + d0] = ov;
          } else {
            int c0 = col0 - s1, h = c0 >> 6, d0 = c0 & 63;
            uint2 ov; ov.x = pk2bf(v0, v1); ov.y = pk2bf(v2, v3);
            *(uint2*)&dk[(((long)b_ * NHEAD + h) * TA_ + t_) * HDIM + d0] = ov;
          }
        }
      } else {     // SWAP == 0, EPI == 2: V^T scatter, t-contiguous
        const int col = (int)blockIdx.y * 256 + wn * 64 + nf * 16 + l15;
        const int row0 = (int)m0 + wm * 128 + mf * 16 + l4 * 4;
        float bv = bias ? bias[col] : 0.f;
        int b_ = row0 >> 9, t0 = row0 & 511;
        int h = col >> 6, d = col & 63;
        uint2 ov;
        ov.x = pk2bf(acc[mf][nf][0] + bv, acc[mf][nf][1] + bv);
        ov.y = pk2bf(acc[mf][nf][2] + bv, acc[mf][nf][3] + bv);
        *(uint2*)&dv[(((long)b_ * NHEAD + h) * HDIM + d) * TA_ + t0] = ov;
      }
    }
}

// ---------------------------------------------------------------- fused attention v9 (round-16 verified, unchanged)
template<int BIAS>
__global__ __launch_bounds__(512) void attn_fused9(
    const unsigned short* __restrict__ Qr, const unsigned short* __restrict__ Kr,
    const unsigned short* __restrict__ Vt, const float* __restrict__ bias2d,
    unsigned short* __restrict__ Orow) {
  __shared__ __align__(16) unsigned short Kb[3][64 * 64];     // 24 KB
  __shared__ __align__(16) unsigned short Vb[3][64 * 64];     // 24 KB
  __shared__ __align__(16) unsigned short P_lds[8][16][64];   // 16 KB
  const int flat = blockIdx.y * 4 + blockIdx.x;     // gridDim.x == 4, 2048 blocks
  const int W = (flat & 7) * 256 + (flat >> 3);     // XCD-chunked (bijective)
  const int bh = W >> 2;
  const int b = bh >> 4, h = bh & 15;
  const int tid = threadIdx.x, w = tid >> 6, lane = tid & 63;   // w in 0..7
  const int l15 = lane & 15, l4 = lane >> 4;
  const int q0 = (W & 3) * 128 + w * 16;            // this wave's 16 q rows

  const unsigned short* Kg = Kr + (long)bh * TA_ * HDIM;
  const unsigned short* Vg = Vt + (long)bh * HDIM * TA_;

  const int stg_row = lane >> 3;
  const int stg_col = ((lane & 7) ^ stg_row) * 8;

  auto stage = [&](int t, int cb) {
    const int kv0 = t * 64;
    int row = w * 8 + stg_row;
    GLOAD_LDS16(Kg + (long)(kv0 + row) * HDIM + stg_col, &Kb[cb][(w * 8) * 64]);
    GLOAD_LDS16(Vg + (long)row * TA_ + kv0 + stg_col,    &Vb[cb][(w * 8) * 64]);
  };

  bfv8 qf[2];
#pragma unroll
  for (int kc = 0; kc < 2; ++kc)
    qf[kc] = *(const bfv8*)&Qr[((long)bh * TM_ + q0 + l15) * HDIM + kc * 32 + l4 * 8];

  float mrun = -1e30f, lrun = 0.f;
  f32x4 o[4] = {};   // o[fd] = O^T[d][q=l15]
  unsigned short* prow = &P_lds[w][l15][0];
  const int swz = (l15 & 7) * 8;
  const float* biasrow = BIAS ? &bias2d[(long)(q0 + l15) * TA_] : nullptr;

  stage(0, 0);
  stage(1, 1);

  for (int t = 0; t < 8; ++t) {
    if (t < 7) asm volatile("s_waitcnt vmcnt(2)" ::: "memory");
    else       asm volatile("s_waitcnt vmcnt(0)" ::: "memory");
    BARRIER;
    if (t + 2 < 8) stage(t + 2, (t + 2) % 3);
    const int cur = t % 3;
    const int kv0 = t * 64;
    f32x4 s[4] = {};
#pragma unroll
    for (int f = 0; f < 4; ++f) {
#pragma unroll
      for (int kc = 0; kc < 2; ++kc) {
        bfv8 kf = *(const bfv8*)&Kb[cur][(f * 16 + l15) * 64 + (((kc * 4 + l4) * 8) ^ swz)];
        s[f] = __builtin_amdgcn_mfma_f32_16x16x32_bf16(kf, qf[kc], s[f], 0, 0, 0);
      }
    }
    if (BIAS) {
#pragma unroll
      for (int f = 0; f < 4; ++f) {
        float4 bv = *(const float4*)&biasrow[kv0 + f * 16 + l4 * 4];
        s[f][0] += bv.x; s[f][1] += bv.y; s[f][2] += bv.z; s[f][3] += bv.w;
      }
    }
    float t0 = fmaxf(fmaxf(s[0][0], s[0][1]), fmaxf(s[0][2], s[0][3]));
    float t1 = fmaxf(fmaxf(s[1][0], s[1][1]), fmaxf(s[1][2], s[1][3]));
    float t2 = fmaxf(fmaxf(s[2][0], s[2][1]), fmaxf(s[2][2], s[2][3]));
    float t3 = fmaxf(fmaxf(s[3][0], s[3][1]), fmaxf(s[3][2], s[3][3]));
    float pmax = fmaxf(fmaxf(t0, t1), fmaxf(t2, t3));
    pmax = fmaxf(pmax, __shfl_xor(pmax, 16));
    pmax = fmaxf(pmax, __shfl_xor(pmax, 32));
    if (!__all(pmax - mrun <= 8.0f)) {
      float newm = fmaxf(mrun, pmax);
      float corr = __expf(mrun - newm);
      lrun *= corr;
#pragma unroll
      for (int fd = 0; fd < 4; ++fd)
#pragma unroll
        for (int r = 0; r < 4; ++r) o[fd][r] *= corr;
      mrun = newm;
    }
    float p0 = 0.f, p1 = 0.f, p2 = 0.f, p3 = 0.f;
#pragma unroll
    for (int f = 0; f < 4; ++f) {
      float e0 = __expf(s[f][0] - mrun), e1 = __expf(s[f][1] - mrun);
      float e2 = __expf(s[f][2] - mrun), e3 = __expf(s[f][3] - mrun);
      p0 += e0; p1 += e1; p2 += e2; p3 += e3;
      unsigned w0 = pk2bf(e0, e1);
      unsigned w1 = pk2bf(e2, e3);
      int blkW = ((f << 1) | (l4 >> 1)) ^ (l15 & 7);
      uint2 pw; pw.x = w0; pw.y = w1;
      *(uint2*)((char*)prow + blkW * 16 + (l4 & 1) * 8) = pw;
    }
    float psum = (p0 + p1) + (p2 + p3);
    psum += __shfl_xor(psum, 16);
    psum += __shfl_xor(psum, 32);
    lrun += psum;
    asm volatile("s_waitcnt lgkmcnt(0)" ::: "memory");
    __builtin_amdgcn_sched_barrier(0);   // rule #18
#pragma unroll
    for (int c = 0; c < 2; ++c) {
      int blkR = ((c << 2) | l4) ^ (l15 & 7);
      bfv8 pa = *(const bfv8*)((const char*)prow + blkR * 16);
#pragma unroll
      for (int fd = 0; fd < 4; ++fd) {
        bfv8 vb = *(const bfv8*)&Vb[cur][(fd * 16 + l15) * 64 + (((c * 4 + l4) * 8) ^ swz)];
        o[fd] = __builtin_amdgcn_mfma_f32_16x16x32_bf16(vb, pa, o[fd], 0, 0, 0);
      }
    }
  }

  float invl = 1.f / lrun;
  const long obase = ((long)b * 512 + q0 + l15) * D_MODEL + h * HDIM;
#pragma unroll
  for (int fd = 0; fd < 4; ++fd) {
    uint2 ov;
    ov.x = pk2bf(o[fd][0] * invl, o[fd][1] * invl);
    ov.y = pk2bf(o[fd][2] * invl, o[fd][3] * invl);
    *(uint2*)&Orow[obase + fd * 16 + l4 * 4] = ov;
  }
}

// ---------------------------------------------------------------- fused residual + LayerNorm
__global__ __launch_bounds__(256) void ln_fused(
    const unsigned short* __restrict__ cin,
    const float* __restrict__ residf, const unsigned short* __restrict__ residb,
    const float* __restrict__ gamma, const float* __restrict__ beta,
    const float* __restrict__ gate,
    float* __restrict__ out_f32, unsigned short* __restrict__ out_bf16,
    int remap_resid, int remap_out) {
  long row = blockIdx.x;
  int t = threadIdx.x;
  int tt = (int)(row & 511), bb = (int)(row >> 9);
  long row_tb = (long)tt * 32 + bb;
  float gf = gate ? tanhf(gate[0]) : 1.0f;
  u16x4 cvb = *(const u16x4*)(cin + row * 1024 + t * 4);
  float c0 = bf2f(cvb[0]), c1 = bf2f(cvb[1]), c2 = bf2f(cvb[2]), c3 = bf2f(cvb[3]);
  float r0, r1, r2, r3;
  if (residf) {
    long rr = remap_resid ? row_tb : row;
    float4 rv = *(const float4*)(residf + rr * 1024 + t * 4);
    r0 = rv.x; r1 = rv.y; r2 = rv.z; r3 = rv.w;
  } else {
    u16x4 rv = *(const u16x4*)(residb + row * 1024 + t * 4);
    r0 = bf2f(rv[0]); r1 = bf2f(rv[1]); r2 = bf2f(rv[2]); r3 = bf2f(rv[3]);
  }
  float y0 = r0 + gf * c0, y1 = r1 + gf * c1, y2 = r2 + gf * c2, y3 = r3 + gf * c3;
  float s = y0 + y1 + y2 + y3;
  float q = y0 * y0 + y1 * y1 + y2 * y2 + y3 * y3;
#pragma unroll
  for (int off = 32; off; off >>= 1) { s += __shfl_xor(s, off); q += __shfl_xor(q, off); }
  __shared__ float sw[4], qw[4];
  int wave = t >> 6;
  if ((t & 63) == 0) { sw[wave] = s; qw[wave] = q; }
  __syncthreads();
  s = sw[0] + sw[1] + sw[2] + sw[3];
  q = qw[0] + qw[1] + qw[2] + qw[3];
  float mean = s * (1.0f / 1024.0f);
  float var = q * (1.0f / 1024.0f) - mean * mean;
  float rstd = rsqrtf(var + 1e-5f);
  float4 g4 = *(const float4*)(gamma + t * 4);
  float4 b4 = *(const float4*)(beta + t * 4);
  float o0 = (y0 - mean) * rstd * g4.x + b4.x;
  float o1 = (y1 - mean) * rstd * g4.y + b4.y;
  float o2 = (y2 - mean) * rstd * g4.z + b4.z;
  float o3 = (y3 - mean) * rstd * g4.w + b4.w;
  if (out_f32) {
    long ro = remap_out ? row_tb : row;
    float4 o = { o0, o1, o2, o3 };
    *(float4*)(out_f32 + ro * 1024 + t * 4) = o;
  }
  if (out_bf16) {
    u16x4 ob = { f2bf(o0), f2bf(o1), f2bf(o2), f2bf(o3) };
    *(u16x4*)(out_bf16 + row * 1024 + t * 4) = ob;
  }
}

// ---------------------------------------------------------------- host
static inline char* wsa(char*& p, size_t bytes) {
  char* r = p;
  p += (bytes + 255) & ~(size_t)255;
  return r;
}

extern "C" void kernel_launch(void* const* d_in, const int* in_sizes, int n_in,
                              void* d_out, int out_size, void* d_ws, size_t ws_size,
                              hipStream_t stream) {
  const float* src      = (const float*)d_in[0];
  const float* audio    = (const float*)d_in[1];
  const int*   beats    = (const int*)d_in[2];
  const float* sa_in_w  = (const float*)d_in[3];
  const float* sa_in_b  = (const float*)d_in[4];
  const float* sa_out_w = (const float*)d_in[5];
  const float* sa_out_b = (const float*)d_in[6];
  const float* ca_in_w  = (const float*)d_in[7];
  const float* ca_in_b  = (const float*)d_in[8];
  const float* ca_out_w = (const float*)d_in[9];
  const float* ca_out_b = (const float*)d_in[10];
  const float* gate     = (const float*)d_in[11];
  const float* n1_g     = (const float*)d_in[12];
  const float* n1_b     = (const float*)d_in[13];
  const float* nc_g     = (const float*)d_in[14];
  const float* nc_b     = (const float*)d_in[15];
  const float* n2_g     = (const float*)d_in[16];
  const float* n2_b     = (const float*)d_in[17];
  const float* l1_w     = (const float*)d_in[18];
  const float* l1_b     = (const float*)d_in[19];
  const float* l2_w     = (const float*)d_in[20];
  const float* l2_b     = (const float*)d_in[21];
  float* out = (float*)d_out;
  (void)in_sizes; (void)n_in; (void)out_size;

  const size_t NEEDED = (size_t)236000000;
  if (ws_size < NEEDED) {
    copy_f32<<<dim3(NTOK), dim3(256), 0, stream>>>(src, out);
    return;
  }

  char* p = (char*)d_ws;
  float*          bias2d = (float*)         wsa(p, (size_t)TM_ * TA_ * 4);
  unsigned short* wsaiw  = (unsigned short*)wsa(p, (size_t)3 * D_MODEL * D_MODEL * 2);
  unsigned short* wsaow  = (unsigned short*)wsa(p, (size_t)D_MODEL * D_MODEL * 2);
  unsigned short* wcaiw  = (unsigned short*)wsa(p, (size_t)3 * D_MODEL * D_MODEL * 2);
  unsigned short* wcaow  = (unsigned short*)wsa(p, (size_t)D_MODEL * D_MODEL * 2);
  unsigned short* wl1    = (unsigned short*)wsa(p, (size_t)DFF_ * D_MODEL * 2);
  unsigned short* wl2    = (unsigned short*)wsa(p, (size_t)D_MODEL * DFF_ * 2);
  unsigned short* srcb   = (unsigned short*)wsa(p, (size_t)NTOK * D_MODEL * 2);
  unsigned short* audb   = (unsigned short*)wsa(p, (size_t)NTOK * D_MODEL * 2);
  // H1 (128 MiB) overlays [Qr | Kr | Vt | x1b]:
  unsigned short* Qr     = (unsigned short*)wsa(p, (size_t)NTOK * D_MODEL * 2);
  unsigned short* Kr     = (unsigned short*)wsa(p, (size_t)NTOK * D_MODEL * 2);
  unsigned short* Vt     = (unsigned short*)wsa(p, (size_t)NTOK * D_MODEL * 2);
  unsigned short* x1b    = (unsigned short*)wsa(p, (size_t)NTOK * D_MODEL * 2);
  unsigned short* Orow   = srcb;
  unsigned short* C1     = Vt;
  unsigned short* x2b    = audb;
  unsigned short* H1     = Qr;
  unsigned short* C2     = srcb;

  // ---- bias + converts (consolidated: 3 launches)
  build_bias<<<dim3(TM_), dim3(TA_), 0, stream>>>(beats, bias2d);
  cvt_remap2<<<dim3(NTOK, 2), dim3(256), 0, stream>>>(src, audio, srcb, audb);
  cvt_weights<<<dim3(16384), dim3(256), 0, stream>>>(
      sa_in_w, sa_out_w, ca_in_w, ca_out_w, l1_w, l2_w,
      wsaiw, wsaow, wcaiw, wcaow, wl1, wl2);

  // ---- self-attention
  gemm256p<3, 1><<<dim3(64, 8), dim3(512), 0, stream>>>(
      srcb, wsaiw, sa_in_b, 1024, nullptr, 0, Qr, Kr, nullptr, 1024);
  gemm256p<2, 0><<<dim3(64, 4), dim3(512), 0, stream>>>(
      srcb, wsaiw + (size_t)2048 * D_MODEL, sa_in_b + 2048, 1024,
      nullptr, 0, nullptr, nullptr, Vt, 0);
  attn_fused9<0><<<dim3(TM_ / 128, BATCH * NHEAD), dim3(512), 0, stream>>>(Qr, Kr, Vt, nullptr, Orow);
  gemm256p<0, 1><<<dim3(64, 4), dim3(512), 0, stream>>>(
      Orow, wsaow, sa_out_b, 1024, C1, 1024, nullptr, nullptr, nullptr, 0);
  ln_fused<<<dim3(NTOK), dim3(256), 0, stream>>>(
      C1, src, nullptr, n1_g, n1_b, nullptr, nullptr, x1b, 1, 0);

  // ---- cross-attention
  gemm256p<3, 1><<<dim3(64, 4), dim3(512), 0, stream>>>(
      x1b, wcaiw, ca_in_b, 1024, nullptr, 0, Qr, nullptr, nullptr, 1024);      // all -> Q
  gemm256p<3, 1><<<dim3(64, 4), dim3(512), 0, stream>>>(
      audb, wcaiw + (size_t)1024 * D_MODEL, ca_in_b + 1024, 1024,
      nullptr, 0, nullptr, Kr, nullptr, 0);                                    // all -> K
  gemm256p<2, 0><<<dim3(64, 4), dim3(512), 0, stream>>>(
      audb, wcaiw + (size_t)2048 * D_MODEL, ca_in_b + 2048, 1024,
      nullptr, 0, nullptr, nullptr, Vt, 0);
  attn_fused9<1><<<dim3(TM_ / 128, BATCH * NHEAD), dim3(512), 0, stream>>>(Qr, Kr, Vt, bias2d, Orow);
  gemm256p<0, 1><<<dim3(64, 4), dim3(512), 0, stream>>>(
      Orow, wcaow, ca_out_b, 1024, C1, 1024, nullptr, nullptr, nullptr, 0);
  ln_fused<<<dim3(NTOK), dim3(256), 0, stream>>>(
      C1, nullptr, x1b, nc_g, nc_b, gate, nullptr, x2b, 0, 0);

  // ---- FFN
  gemm256p<1, 1><<<dim3(64, 16), dim3(512), 0, stream>>>(
      x2b, wl1, l1_b, 1024, H1, DFF_, nullptr, nullptr, nullptr, 0);
  gemm256p<0, 1><<<dim3(64, 4), dim3(512), 0, stream>>>(
      H1, wl2, l2_b, DFF_, C2, 1024, nullptr, nullptr, nullptr, 0);
  ln_fused<<<dim3(NTOK), dim3(256), 0, stream>>>(
      C2, nullptr, x2b, n2_g, n2_b, nullptr, out, nullptr, 0, 1);
}